// Round 6
// baseline (891.713 us; speedup 1.0000x reference)
//
#include <hip/hip_runtime.h>
#include <hip/hip_cooperative_groups.h>

namespace cg = cooperative_groups;

// Problem constants (from reference)
constexpr int NN = 50000;   // nodes
constexpr int NE = 800000;  // edges
constexpr int CI = 16;      // in channels
constexpr int CO = 64;      // out channels
constexpr int DD = 7;       // decoder dim

// Binned counting-sort geometry (no global atomics anywhere)
constexpr int NBUCK = 196;                       // node buckets: n>>8, 50000/256
constexpr int EPB   = 4096;                      // edges per binning block
constexpr int NBLK3 = (NE + EPB - 1) / EPB;      // 196 binning blocks
constexpr int TBL   = NBUCK * NBLK3;             // 38416 table entries

typedef __bf16 bf16x8 __attribute__((ext_vector_type(8)));
typedef float  f32x4  __attribute__((ext_vector_type(4)));
typedef float  f32x2  __attribute__((ext_vector_type(2)));

__device__ inline float blo(unsigned u) { return __uint_as_float(u << 16); }
__device__ inline float bhi(unsigned u) { return __uint_as_float(u & 0xffff0000u); }

// fp8 e4m3 helpers (HW packed converts; OCP format on gfx950)
__device__ inline void acc8_fp8(float acc[8], float w, uint2 u) {
    f32x2 c;
    c = __builtin_amdgcn_cvt_pk_f32_fp8(u.x, false); acc[0] += w * c[0]; acc[1] += w * c[1];
    c = __builtin_amdgcn_cvt_pk_f32_fp8(u.x, true);  acc[2] += w * c[0]; acc[3] += w * c[1];
    c = __builtin_amdgcn_cvt_pk_f32_fp8(u.y, false); acc[4] += w * c[0]; acc[5] += w * c[1];
    c = __builtin_amdgcn_cvt_pk_f32_fp8(u.y, true);  acc[6] += w * c[0]; acc[7] += w * c[1];
}
__device__ inline uint2 pack_fp8x8(const float o[8]) {
    int t0 = __builtin_amdgcn_cvt_pk_fp8_f32(o[0], o[1], 0, false);
    t0 = __builtin_amdgcn_cvt_pk_fp8_f32(o[2], o[3], t0, true);
    int t1 = __builtin_amdgcn_cvt_pk_fp8_f32(o[4], o[5], 0, false);
    t1 = __builtin_amdgcn_cvt_pk_fp8_f32(o[6], o[7], t1, true);
    uint2 r; r.x = (unsigned)t0; r.y = (unsigned)t1; return r;
}
__device__ inline unsigned char fp8_of(float v) {
    return (unsigned char)(__builtin_amdgcn_cvt_pk_fp8_f32(v, v, 0, false) & 0xff);
}

constexpr int XOCT = NN * CI / 8;              // 100000 octets in x
constexpr int HOCT = NN * CO / 8;              // 400000 octets in h0
constexpr int CB = (XOCT + HOCT + 255) / 256;  // 1954 cast blocks

// ===================== shared device task bodies =====================

__device__ inline void task_cast(int t, const float* __restrict__ x, const float* __restrict__ h0,
                                 __bf16* __restrict__ x_bf, __bf16* __restrict__ h0_bf,
                                 unsigned char* __restrict__ h0_f8) {
    if (t < XOCT) {
        const float* sp = x + (size_t)t * 8;
        float4 a = *(const float4*)sp;
        float4 c = *(const float4*)(sp + 4);
        bf16x8 o;
        o[0] = (__bf16)a.x; o[1] = (__bf16)a.y; o[2] = (__bf16)a.z; o[3] = (__bf16)a.w;
        o[4] = (__bf16)c.x; o[5] = (__bf16)c.y; o[6] = (__bf16)c.z; o[7] = (__bf16)c.w;
        *(bf16x8*)(x_bf + (size_t)t * 8) = o;
    } else if (t < XOCT + HOCT) {
        int u = t - XOCT;
        const float* sp = h0 + (size_t)u * 8;
        float4 a = *(const float4*)sp;
        float4 c = *(const float4*)(sp + 4);
        bf16x8 o;
        o[0] = (__bf16)a.x; o[1] = (__bf16)a.y; o[2] = (__bf16)a.z; o[3] = (__bf16)a.w;
        o[4] = (__bf16)c.x; o[5] = (__bf16)c.y; o[6] = (__bf16)c.z; o[7] = (__bf16)c.w;
        *(bf16x8*)(h0_bf + (size_t)u * 8) = o;
        float f[8] = {a.x, a.y, a.z, a.w, c.x, c.y, c.z, c.w};
        *(uint2*)(h0_f8 + (size_t)u * 8) = pack_fp8x8(f);
    }
}

__device__ inline void task_bprep(int tid, const float* __restrict__ Wx, const float* __restrict__ Wh,
                                  const float* __restrict__ bx, const float* __restrict__ bh,
                                  bf16x8* __restrict__ BfragZR, bf16x8* __restrict__ BfragHT,
                                  float* __restrict__ biasC) {
    if (tid < 6144) {
        int e = tid, gate, n, kk, l;
        if (e < 4096) {
            int t = e >> 9, rem = e & 511;
            kk = rem >> 6; l = rem & 63;
            n = t * 16 + (l & 15);
            gate = n >> 6;
        } else {
            int e2 = e - 4096;
            int t = e2 >> 9, rem = e2 & 511;
            kk = rem >> 6; l = rem & 63;
            n = t * 16 + (l & 15);
            gate = 2;
        }
        int co = n & 63;
        int k0 = kk * 32 + (l >> 4) * 8;
        bf16x8 f;
#pragma unroll
        for (int j = 0; j < 8; j++) {
            int k = k0 + j;
            float w = 0.f;
            if (k < 48) {
                int kb = k >> 4, ci = k & 15;
                const float* Wg = Wx + gate * 3 * 16 * 64;
                float w0 = Wg[(kb * 16 + ci) * 64 + co];
                if (kb == 0)      w = w0 - Wg[(2 * 16 + ci) * 64 + co];
                else if (kb == 1) w = w0;
                else              w = 2.f * w0;
            } else if (k < 240) {
                int kh = k - 48, kb = kh >> 6, ci = kh & 63;
                const float* Wg = Wh + gate * 3 * 64 * 64;
                float w0 = Wg[(kb * 64 + ci) * 64 + co];
                if (kb == 0)      w = w0 - Wg[(2 * 64 + ci) * 64 + co];
                else if (kb == 1) w = w0;
                else              w = 2.f * w0;
            }
            f[j] = (__bf16)w;
        }
        if (e < 4096) BfragZR[e] = f; else BfragHT[e - 4096] = f;
    } else if (tid < 6144 + 192) {
        int i = tid - 6144;
        biasC[i] = bx[i] + bh[i];
    }
}

// ============ propagation bodies (pure) ============
// out[n] = -dinv[n] * sum_{e in row n} w'_e * v[src_e]
// Row metadata (deg<=64 in practice) preloaded with one coalesced load; gather loop
// gets meta via __shfl so all v-gathers pipeline. Padded lanes carry w=+0,s=0 (no-op).

__device__ inline void fprop_body(int n, int lane,
                                  const unsigned char* __restrict__ vh8,
                                  const __bf16* __restrict__ vx,
                                  const float* __restrict__ dinv,
                                  const int* __restrict__ rowptr,
                                  const unsigned* __restrict__ ew,
                                  __bf16* __restrict__ outh_bf,
                                  unsigned char* __restrict__ outh_f8,
                                  __bf16* __restrict__ outx) {
    int j = lane >> 3, cg = lane & 7;
    int beg = rowptr[n], end = rowptr[n + 1];
    float f = -dinv[n];
    unsigned pmeta = (beg + lane < end) ? ew[beg + lane] : 0u;
    int deg = end - beg;
    int nIt = (deg >= 64) ? 8 : ((deg + 7) >> 3);
    float acc[8] = {0.f, 0.f, 0.f, 0.f, 0.f, 0.f, 0.f, 0.f};
    float ax0 = 0.f, ax1 = 0.f;
#pragma unroll
    for (int t = 0; t < 8; t++) {
        if (t < nIt) {
            unsigned p = __shfl(pmeta, j + 8 * t, 64);
            float w = bhi(p);
            int s = p & 0xffff;
            uint2 u = *(const uint2*)(vh8 + (size_t)s * 64 + cg * 8);
            unsigned xv = *(const unsigned*)((const char*)vx + ((size_t)s * 32 + cg * 4));
            acc8_fp8(acc, w, u);
            ax0 += w * blo(xv);
            ax1 += w * bhi(xv);
        }
    }
    for (int e = beg + 64 + j; e < end; e += 8) {
        unsigned p = ew[e];
        float w = bhi(p);
        int s = p & 0xffff;
        uint2 u = *(const uint2*)(vh8 + (size_t)s * 64 + cg * 8);
        unsigned xv = *(const unsigned*)((const char*)vx + ((size_t)s * 32 + cg * 4));
        acc8_fp8(acc, w, u);
        ax0 += w * blo(xv);
        ax1 += w * bhi(xv);
    }
#pragma unroll
    for (int m = 8; m <= 32; m <<= 1) {
#pragma unroll
        for (int i = 0; i < 8; i++) acc[i] += __shfl_xor(acc[i], m, 64);
        ax0 += __shfl_xor(ax0, m, 64);
        ax1 += __shfl_xor(ax1, m, 64);
    }
    if (lane < 8) {
        float o[8];
#pragma unroll
        for (int i = 0; i < 8; i++) o[i] = f * acc[i];
        bf16x8 st;
#pragma unroll
        for (int i = 0; i < 8; i++) st[i] = (__bf16)o[i];
        *(bf16x8*)(outh_bf + (size_t)n * 64 + lane * 8) = st;
        if (outh_f8) *(uint2*)(outh_f8 + (size_t)n * 64 + lane * 8) = pack_fp8x8(o);
        __bf16 b0 = (__bf16)(f * ax0), b1 = (__bf16)(f * ax1);
        unsigned pk = (unsigned)__builtin_bit_cast(unsigned short, b0)
                    | ((unsigned)__builtin_bit_cast(unsigned short, b1) << 16);
        *(unsigned*)((char*)outx + (size_t)n * 32 + lane * 4) = pk;
    }
}

__device__ inline void prop64_body(int n, int lane,
                                   const unsigned char* __restrict__ v8,
                                   const float* __restrict__ dinv,
                                   const int* __restrict__ rowptr,
                                   const unsigned* __restrict__ ew,
                                   __bf16* __restrict__ out_bf,
                                   unsigned char* __restrict__ out_f8) {
    int j = lane >> 3, cg = lane & 7;
    int beg = rowptr[n], end = rowptr[n + 1];
    float f = -dinv[n];
    unsigned pmeta = (beg + lane < end) ? ew[beg + lane] : 0u;
    int deg = end - beg;
    int nIt = (deg >= 64) ? 8 : ((deg + 7) >> 3);
    float acc[8] = {0.f, 0.f, 0.f, 0.f, 0.f, 0.f, 0.f, 0.f};
#pragma unroll
    for (int t = 0; t < 8; t++) {
        if (t < nIt) {
            unsigned p = __shfl(pmeta, j + 8 * t, 64);
            float w = bhi(p);
            int s = p & 0xffff;
            uint2 u = *(const uint2*)(v8 + (size_t)s * 64 + cg * 8);
            acc8_fp8(acc, w, u);
        }
    }
    for (int e = beg + 64 + j; e < end; e += 8) {
        unsigned p = ew[e];
        float w = bhi(p);
        int s = p & 0xffff;
        uint2 u = *(const uint2*)(v8 + (size_t)s * 64 + cg * 8);
        acc8_fp8(acc, w, u);
    }
#pragma unroll
    for (int m = 8; m <= 32; m <<= 1) {
#pragma unroll
        for (int i = 0; i < 8; i++) acc[i] += __shfl_xor(acc[i], m, 64);
    }
    if (lane < 8) {
        float o[8];
#pragma unroll
        for (int i = 0; i < 8; i++) o[i] = f * acc[i];
        bf16x8 st;
#pragma unroll
        for (int i = 0; i < 8; i++) st[i] = (__bf16)o[i];
        *(bf16x8*)(out_bf + (size_t)n * 64 + lane * 8) = st;
        if (out_f8) *(uint2*)(out_f8 + (size_t)n * 64 + lane * 8) = pack_fp8x8(o);
    }
}

// ============ MFMA gate wave bodies ============
// Logical A row (K=256): [x(16)|Px(16)|P2x(16)|H(64)|PH(64)|P2H(64)|pad(16)], bf16 flat.

__device__ inline bf16x8 load_a_bf(int c, int m,
                                   const __bf16* __restrict__ xb, const __bf16* __restrict__ t1,
                                   const __bf16* __restrict__ t2, const __bf16* __restrict__ hb,
                                   const __bf16* __restrict__ h1, const __bf16* __restrict__ h2) {
    if (c >= 30) {
        bf16x8 a;
#pragma unroll
        for (int j = 0; j < 8; j++) a[j] = (__bf16)0.f;
        return a;
    }
    if (c < 6) {
        const __bf16* base = (c < 2) ? xb : ((c < 4) ? t1 : t2);
        return *(const bf16x8*)(base + (size_t)m * 16 + (c & 1) * 8);
    }
    int d = c - 6;
    const __bf16* base = (d < 8) ? hb : ((d < 16) ? h1 : h2);
    return *(const bf16x8*)(base + (size_t)m * 64 + (d & 7) * 8);
}

__device__ inline void zr_wave(int wv, int lane,
    const __bf16* __restrict__ xb, const __bf16* __restrict__ t1, const __bf16* __restrict__ t2,
    const __bf16* __restrict__ hb, const __bf16* __restrict__ h1, const __bf16* __restrict__ h2,
    const bf16x8* __restrict__ Bfrag, const float* __restrict__ biasC,
    __bf16* __restrict__ z_bf, __bf16* __restrict__ hr_bf, unsigned char* __restrict__ hr_f8) {
    int q = lane >> 4, r16 = lane & 15;
    int ma = wv * 16 + r16;
    f32x4 acc[8];
#pragma unroll
    for (int t = 0; t < 8; t++) acc[t] = (f32x4){0.f, 0.f, 0.f, 0.f};
#pragma unroll
    for (int kk = 0; kk < 8; kk++) {
        bf16x8 a = load_a_bf(kk * 4 + q, ma, xb, t1, t2, hb, h1, h2);
#pragma unroll
        for (int t = 0; t < 8; t++)
            acc[t] = __builtin_amdgcn_mfma_f32_16x16x32_bf16(a, Bfrag[(t * 8 + kk) * 64 + lane], acc[t], 0, 0, 0);
    }
    int mbase = wv * 16 + q * 4;
#pragma unroll
    for (int t = 0; t < 8; t++) {
        int co = t * 16 + r16;      // 0..127
        float bias = biasC[co];
        int col = co & 63;
#pragma unroll
        for (int reg = 0; reg < 4; reg++) {
            int mm = mbase + reg;
            float p = acc[t][reg] + bias;
            float s = 1.f / (1.f + __expf(-p));
            if (t < 4) z_bf[(size_t)mm * 64 + col] = (__bf16)s;
            else {
                float hrv = s * (float)hb[(size_t)mm * 64 + col];
                hr_bf[(size_t)mm * 64 + col] = (__bf16)hrv;
                hr_f8[(size_t)mm * 64 + col] = fp8_of(hrv);
            }
        }
    }
}

__device__ inline void ht_wave(int wv, int lane,
    const __bf16* __restrict__ xb, const __bf16* __restrict__ t1, const __bf16* __restrict__ t2,
    const __bf16* __restrict__ hrb, const __bf16* __restrict__ r1, const __bf16* __restrict__ r2,
    const bf16x8* __restrict__ Bfrag, const float* __restrict__ biasC,
    const __bf16* __restrict__ z_bf, const float* __restrict__ h0,
    const float* __restrict__ Wlin, const float* __restrict__ blin,
    float* __restrict__ hout, float* __restrict__ yout) {
    int q = lane >> 4, r16 = lane & 15;
    int ma = wv * 16 + r16;
    f32x4 acc[4];
#pragma unroll
    for (int t = 0; t < 4; t++) acc[t] = (f32x4){0.f, 0.f, 0.f, 0.f};
#pragma unroll
    for (int kk = 0; kk < 8; kk++) {
        bf16x8 a = load_a_bf(kk * 4 + q, ma, xb, t1, t2, hrb, r1, r2);
#pragma unroll
        for (int t = 0; t < 4; t++)
            acc[t] = __builtin_amdgcn_mfma_f32_16x16x32_bf16(a, Bfrag[(t * 8 + kk) * 64 + lane], acc[t], 0, 0, 0);
    }
    int mbase = wv * 16 + q * 4;
    float hbuf[4][4];
#pragma unroll
    for (int t = 0; t < 4; t++) {
        int co = t * 16 + r16;   // 0..63
        float bias = biasC[128 + co];
#pragma unroll
        for (int reg = 0; reg < 4; reg++) {
            int mm = mbase + reg;
            float p = acc[t][reg] + bias;
            float htl = tanhf(p);
            float zv = (float)z_bf[(size_t)mm * 64 + co];
            float h0v = h0[(size_t)mm * 64 + co];
            float hn = zv * h0v + (1.f - zv) * htl;
            hout[(size_t)mm * 64 + co] = hn;
            hbuf[t][reg] = hn;
        }
    }
    float ya[4][DD];
#pragma unroll
    for (int reg = 0; reg < 4; reg++)
#pragma unroll
        for (int d = 0; d < DD; d++) ya[reg][d] = 0.f;
#pragma unroll
    for (int t = 0; t < 4; t++) {
        int cb = (t * 16 + r16) * DD;
        float wl[DD];
#pragma unroll
        for (int d = 0; d < DD; d++) wl[d] = Wlin[cb + d];
#pragma unroll
        for (int reg = 0; reg < 4; reg++) {
            float rh = fmaxf(hbuf[t][reg], 0.f);
#pragma unroll
            for (int d = 0; d < DD; d++) ya[reg][d] += rh * wl[d];
        }
    }
#pragma unroll
    for (int m = 1; m <= 8; m <<= 1) {
#pragma unroll
        for (int reg = 0; reg < 4; reg++)
#pragma unroll
            for (int d = 0; d < DD; d++) ya[reg][d] += __shfl_xor(ya[reg][d], m, 64);
    }
    if (r16 < DD) {
        float b = blin[r16];
#pragma unroll
        for (int reg = 0; reg < 4; reg++) {
            float v = (r16 == 0) ? ya[reg][0] : (r16 == 1) ? ya[reg][1] : (r16 == 2) ? ya[reg][2]
                    : (r16 == 3) ? ya[reg][3] : (r16 == 4) ? ya[reg][4] : (r16 == 5) ? ya[reg][5]
                    : ya[reg][6];
            yout[(size_t)(mbase + reg) * DD + r16] = v + b;
        }
    }
}

// ===================== cooperative megakernel =====================

struct MegaArgs {
    const int* src; const int* dst; const float* ew;
    const float* x; const float* h0;
    const float* Wx; const float* Wh; const float* bx; const float* bh;
    const float* Wlin; const float* blin;
    int* Cd; int* Cs; int* CdRow; int* CsRow; int* CdBase; int* CsBase;
    uint2* drec; unsigned* srec; float* dinv; int* rowptr; unsigned* csr_ew;
    __bf16* x_bf; __bf16* h0_bf; unsigned char* h0_f8;
    unsigned char* T1_f8; unsigned char* hr_f8;
    __bf16* Tx1; __bf16* Tx2; __bf16* Th1; __bf16* Th2;
    __bf16* hr_bf; __bf16* z_bf;
    bf16x8* BfragZR; bf16x8* BfragHT; float* biasC;
    float* hout; float* yout;
};

// exclusive-scan of n (<=256) ints in[] -> out[] (in-place ok); total -> *tot
__device__ inline void task_exscan(const int* in, int* out, int n, int* tot, int* lds, int tid) {
    int v = (tid < n) ? in[tid] : 0;
    lds[tid] = v;
    __syncthreads();
    for (int off = 1; off < 256; off <<= 1) {
        int p = (tid >= off) ? lds[tid - off] : 0;
        __syncthreads();
        lds[tid] += p;
        __syncthreads();
    }
    if (tid < n) out[tid] = lds[tid] - v;
    if (tot && tid == 0) *tot = lds[255];
    __syncthreads();
}

__global__ void __launch_bounds__(256, 4) k_mega(MegaArgs A) {
    cg::grid_group grid = cg::this_grid();
    const int nb  = (int)gridDim.x;
    const int bid = (int)blockIdx.x;
    const int tid = (int)threadIdx.x;
    const int wid = tid >> 6, lane = tid & 63;

    __shared__ union {
        struct { int hd[NBUCK], hs[NBUCK]; } h;
        int scan[256];
        struct { int cd[NBUCK], cs[NBUCK]; } c;
        float dacc[256];
        struct { int cnt[256], sc[256], cur[256]; } b;
    } sm;

    // ---- P1: bucket histograms + casts + B-prep ----
    for (int b = bid; b < NBLK3 + CB + 25; b += nb) {
        if (b < NBLK3) {
            for (int i = tid; i < NBUCK; i += 256) { sm.h.hd[i] = 0; sm.h.hs[i] = 0; }
            __syncthreads();
            int base = b * EPB;
#pragma unroll
            for (int k = 0; k < EPB / 256; k++) {
                int e = base + k * 256 + tid;
                if (e < NE) {
                    atomicAdd(&sm.h.hd[A.dst[e] >> 8], 1);
                    atomicAdd(&sm.h.hs[A.src[e] >> 8], 1);
                }
            }
            __syncthreads();
            for (int i = tid; i < NBUCK; i += 256) {
                A.Cd[i * NBLK3 + b] = sm.h.hd[i];
                A.Cs[i * NBLK3 + b] = sm.h.hs[i];
            }
            __syncthreads();
        } else if (b < NBLK3 + CB) {
            task_cast((b - NBLK3) * 256 + tid, A.x, A.h0, A.x_bf, A.h0_bf, A.h0_f8);
        } else {
            task_bprep((b - NBLK3 - CB) * 256 + tid, A.Wx, A.Wh, A.bx, A.bh,
                       A.BfragZR, A.BfragHT, A.biasC);
        }
    }
    grid.sync();

    // ---- P2a: per-row exclusive scan of both tables (within-row) ----
    for (int t = bid; t < 2 * NBUCK; t += nb) {
        int* C   = (t < NBUCK) ? A.Cd : A.Cs;
        int* Row = (t < NBUCK) ? A.CdRow : A.CsRow;
        int row  = (t < NBUCK) ? t : t - NBUCK;
        task_exscan(&C[row * NBLK3], &C[row * NBLK3], NBLK3, &Row[row], sm.scan, tid);
    }
    grid.sync();

    // ---- P2b: exclusive scan of row totals -> bucket segment bases ----
    for (int t = bid; t < 2; t += nb) {
        int* Row  = (t == 0) ? A.CdRow : A.CsRow;
        int* Base = (t == 0) ? A.CdBase : A.CsBase;
        task_exscan(Row, Base, NBUCK, nullptr, sm.scan, tid);
    }
    grid.sync();

    // ---- P3: scatter edge records into bucket segments ----
    for (int b = bid; b < NBLK3; b += nb) {
        for (int i = tid; i < NBUCK; i += 256) {
            sm.c.cd[i] = A.CdBase[i] + A.Cd[i * NBLK3 + b];
            sm.c.cs[i] = A.CsBase[i] + A.Cs[i * NBLK3 + b];
        }
        __syncthreads();
        int base = b * EPB;
#pragma unroll
        for (int k = 0; k < EPB / 256; k++) {
            int e = base + k * 256 + tid;
            if (e < NE) {
                int s = A.src[e], d = A.dst[e];
                float w = (s == d) ? 0.f : A.ew[e];
                __bf16 wb = (__bf16)w;
                unsigned wu = (unsigned)__builtin_bit_cast(unsigned short, wb);
                int pd = atomicAdd(&sm.c.cd[d >> 8], 1);
                A.drec[pd] = make_uint2((unsigned)s | (wu << 16), (unsigned)(d & 255));
                int ps = atomicAdd(&sm.c.cs[s >> 8], 1);
                A.srec[ps] = (__builtin_bit_cast(unsigned, w) & 0xFFFFFF00u) | (unsigned)(s & 255);
            }
        }
        __syncthreads();
    }
    grid.sync();

    // ---- P4: per-src-bucket degree accumulation -> dinv ----
    for (int bkt = bid; bkt < NBUCK; bkt += nb) {
        sm.dacc[tid] = 0.f;
        __syncthreads();
        int beg = A.CsBase[bkt], end = beg + A.CsRow[bkt];
        for (int i = beg + tid; i < end; i += 256) {
            unsigned r = A.srec[i];
            atomicAdd(&sm.dacc[r & 255], __uint_as_float(r & 0xFFFFFF00u));
        }
        __syncthreads();
        int node = bkt * 256 + tid;
        if (node < NN) {
            float dsum = sm.dacc[tid];
            A.dinv[node] = (dsum > 0.f) ? (1.f / sqrtf(dsum)) : 0.f;
        }
        __syncthreads();
    }
    grid.sync();

    // ---- P5: per-dst-bucket counting sort -> rowptr + csr_ew (dinv folded) ----
    for (int bkt = bid; bkt < NBUCK; bkt += nb) {
        sm.b.cnt[tid] = 0;
        __syncthreads();
        int beg = A.CdBase[bkt], end = beg + A.CdRow[bkt];
        for (int i = beg + tid; i < end; i += 256) atomicAdd(&sm.b.cnt[A.drec[i].y], 1);
        __syncthreads();
        int val = sm.b.cnt[tid];
        sm.b.sc[tid] = val;
        __syncthreads();
        for (int off = 1; off < 256; off <<= 1) {
            int p = (tid >= off) ? sm.b.sc[tid - off] : 0;
            __syncthreads();
            sm.b.sc[tid] += p;
            __syncthreads();
        }
        int ex = sm.b.sc[tid] - val;
        int node = bkt * 256 + tid;
        if (node <= NN) A.rowptr[node] = beg + ex;
        sm.b.cur[tid] = ex;
        __syncthreads();
        for (int i = beg + tid; i < end; i += 256) {
            uint2 r = A.drec[i];
            int slot = beg + atomicAdd(&sm.b.cur[r.y], 1);
            unsigned s = r.x & 0xffff;
            float w = bhi(r.x);
            float wp = A.dinv[s] * w;
            __bf16 wb = (__bf16)wp;
            A.csr_ew[slot] = s | ((unsigned)__builtin_bit_cast(unsigned short, wb) << 16);
        }
        __syncthreads();
    }
    grid.sync();

    // ---- P6: P(h0) + P(x) ----
    for (int base = bid * 4; base < NN; base += nb * 4) {
        int n = base + wid;
        if (n < NN) fprop_body(n, lane, A.h0_f8, A.x_bf, A.dinv, A.rowptr, A.csr_ew,
                               A.Th1, A.T1_f8, A.Tx1);
    }
    grid.sync();

    // ---- P7: P^2(h0) + P^2(x) ----
    for (int base = bid * 4; base < NN; base += nb * 4) {
        int n = base + wid;
        if (n < NN) fprop_body(n, lane, A.T1_f8, A.Tx1, A.dinv, A.rowptr, A.csr_ew,
                               A.Th2, nullptr, A.Tx2);
    }
    grid.sync();

    // ---- P8: z and r gates (r fused into hr = r*h0) ----
    for (int wv = bid * 4 + wid; wv < NN / 16; wv += nb * 4) {
        zr_wave(wv, lane, A.x_bf, A.Tx1, A.Tx2, A.h0_bf, A.Th1, A.Th2,
                A.BfragZR, A.biasC, A.z_bf, A.hr_bf, A.hr_f8);
    }
    grid.sync();

    // ---- P9: P(hr) ----
    for (int base = bid * 4; base < NN; base += nb * 4) {
        int n = base + wid;
        if (n < NN) prop64_body(n, lane, A.hr_f8, A.dinv, A.rowptr, A.csr_ew, A.Th1, A.T1_f8);
    }
    grid.sync();

    // ---- P10: P^2(hr) ----
    for (int base = bid * 4; base < NN; base += nb * 4) {
        int n = base + wid;
        if (n < NN) prop64_body(n, lane, A.T1_f8, A.dinv, A.rowptr, A.csr_ew, A.Th2, nullptr);
    }
    grid.sync();

    // ---- P11: htilde gate + GRU combine + fused decoder ----
    for (int wv = bid * 4 + wid; wv < NN / 16; wv += nb * 4) {
        ht_wave(wv, lane, A.x_bf, A.Tx1, A.Tx2, A.hr_bf, A.Th1, A.Th2,
                A.BfragHT, A.biasC, A.z_bf, A.h0, A.Wlin, A.blin, A.hout, A.yout);
    }
}

// ===================== fallback discrete kernels (previous passing pipeline) =====================

__global__ void __launch_bounds__(256) k_count(
    const int* __restrict__ src, const int* __restrict__ dst,
    int* __restrict__ Cd, int* __restrict__ Cs,
    const float* __restrict__ x, const float* __restrict__ h0,
    __bf16* __restrict__ x_bf, __bf16* __restrict__ h0_bf, unsigned char* __restrict__ h0_f8,
    const float* __restrict__ Wx, const float* __restrict__ Wh,
    const float* __restrict__ bx, const float* __restrict__ bh,
    bf16x8* __restrict__ BfragZR, bf16x8* __restrict__ BfragHT, float* __restrict__ biasC) {
    int b = blockIdx.x;
    if (b < NBLK3) {
        __shared__ int hd[NBUCK], hs[NBUCK];
        for (int i = threadIdx.x; i < NBUCK; i += 256) { hd[i] = 0; hs[i] = 0; }
        __syncthreads();
        int base = b * EPB;
#pragma unroll
        for (int k = 0; k < EPB / 256; k++) {
            int e = base + k * 256 + threadIdx.x;
            if (e < NE) {
                atomicAdd(&hd[dst[e] >> 8], 1);
                atomicAdd(&hs[src[e] >> 8], 1);
            }
        }
        __syncthreads();
        for (int i = threadIdx.x; i < NBUCK; i += 256) {
            Cd[i * NBLK3 + b] = hd[i];
            Cs[i * NBLK3 + b] = hs[i];
        }
    } else if (b < NBLK3 + CB) {
        task_cast((b - NBLK3) * 256 + threadIdx.x, x, h0, x_bf, h0_bf, h0_f8);
    } else {
        task_bprep((b - NBLK3 - CB) * 256 + threadIdx.x, Wx, Wh, bx, bh, BfragZR, BfragHT, biasC);
    }
}

__global__ void __launch_bounds__(1024) k_scan_tables(int* __restrict__ Cd, int* __restrict__ Cs) {
    int* C = (blockIdx.x == 0) ? Cd : Cs;
    constexpr int CHUNK = (TBL + 1023) / 1024;  // 38
    __shared__ int part[1024];
    int t = threadIdx.x;
    int base = t * CHUNK;
    int v[CHUNK];
    int s = 0;
#pragma unroll
    for (int j = 0; j < CHUNK; j++) {
        int idx = base + j;
        int xv = (idx < TBL) ? C[idx] : 0;
        v[j] = s;
        s += xv;
    }
    part[t] = s;
    __syncthreads();
    for (int off = 1; off < 1024; off <<= 1) {
        int p = (t >= off) ? part[t - off] : 0;
        __syncthreads();
        part[t] += p;
        __syncthreads();
    }
    int tb = (t > 0) ? part[t - 1] : 0;
#pragma unroll
    for (int j = 0; j < CHUNK; j++) {
        int idx = base + j;
        if (idx < TBL) C[idx] = tb + v[j];
    }
}

__global__ void __launch_bounds__(256) k_scatter(
    const int* __restrict__ src, const int* __restrict__ dst, const float* __restrict__ ew,
    const int* __restrict__ Cd, const int* __restrict__ Cs,
    uint2* __restrict__ drec, unsigned* __restrict__ srec) {
    __shared__ int cd[NBUCK], cs[NBUCK];
    int b = blockIdx.x;
    for (int i = threadIdx.x; i < NBUCK; i += 256) {
        cd[i] = Cd[i * NBLK3 + b];
        cs[i] = Cs[i * NBLK3 + b];
    }
    __syncthreads();
    int base = b * EPB;
#pragma unroll
    for (int k = 0; k < EPB / 256; k++) {
        int e = base + k * 256 + threadIdx.x;
        if (e < NE) {
            int s = src[e], d = dst[e];
            float w = (s == d) ? 0.f : ew[e];
            __bf16 wb = (__bf16)w;
            unsigned wu = (unsigned)__builtin_bit_cast(unsigned short, wb);
            int pd = atomicAdd(&cd[d >> 8], 1);
            drec[pd] = make_uint2((unsigned)s | (wu << 16), (unsigned)(d & 255));
            int ps = atomicAdd(&cs[s >> 8], 1);
            srec[ps] = (__builtin_bit_cast(unsigned, w) & 0xFFFFFF00u) | (unsigned)(s & 255);
        }
    }
}

__global__ void __launch_bounds__(256) k_dinv(
    const int* __restrict__ Cs, const unsigned* __restrict__ srec, float* __restrict__ dinv) {
    int bkt = blockIdx.x;
    __shared__ float acc[256];
    acc[threadIdx.x] = 0.f;
    __syncthreads();
    int beg = Cs[bkt * NBLK3];
    int end = (bkt == NBUCK - 1) ? NE : Cs[(bkt + 1) * NBLK3];
    for (int i = beg + threadIdx.x; i < end; i += 256) {
        unsigned r = srec[i];
        atomicAdd(&acc[r & 255], __uint_as_float(r & 0xFFFFFF00u));
    }
    __syncthreads();
    int node = bkt * 256 + threadIdx.x;
    if (node < NN) {
        float dsum = acc[threadIdx.x];
        dinv[node] = (dsum > 0.f) ? (1.f / sqrtf(dsum)) : 0.f;
    }
}

__global__ void __launch_bounds__(256) k_build(
    const int* __restrict__ Cd, const uint2* __restrict__ drec, const float* __restrict__ dinv,
    int* __restrict__ rowptr, unsigned* __restrict__ csr_ew) {
    int bkt = blockIdx.x;
    __shared__ int cnt[256], sc[256], cur[256];
    int t = threadIdx.x;
    cnt[t] = 0;
    __syncthreads();
    int beg = Cd[bkt * NBLK3];
    int end = (bkt == NBUCK - 1) ? NE : Cd[(bkt + 1) * NBLK3];
    for (int i = beg + t; i < end; i += 256) atomicAdd(&cnt[drec[i].y], 1);
    __syncthreads();
    int val = cnt[t];
    sc[t] = val;
    __syncthreads();
    for (int off = 1; off < 256; off <<= 1) {
        int p = (t >= off) ? sc[t - off] : 0;
        __syncthreads();
        sc[t] += p;
        __syncthreads();
    }
    int ex = sc[t] - val;
    int node = bkt * 256 + t;
    if (node <= NN) rowptr[node] = beg + ex;
    cur[t] = ex;
    __syncthreads();
    for (int i = beg + t; i < end; i += 256) {
        uint2 r = drec[i];
        int slot = beg + atomicAdd(&cur[r.y], 1);
        unsigned s = r.x & 0xffff;
        float w = bhi(r.x);
        float wp = dinv[s] * w;
        __bf16 wb = (__bf16)wp;
        csr_ew[slot] = s | ((unsigned)__builtin_bit_cast(unsigned short, wb) << 16);
    }
}

__global__ void __launch_bounds__(256) k_fprop(
    const unsigned char* __restrict__ vh8, const __bf16* __restrict__ vx,
    const float* __restrict__ dinv,
    const int* __restrict__ rowptr, const unsigned* __restrict__ ew,
    __bf16* __restrict__ outh_bf, unsigned char* __restrict__ outh_f8,
    __bf16* __restrict__ outx) {
    int n = blockIdx.x * 4 + (threadIdx.x >> 6);
    if (n >= NN) return;
    fprop_body(n, threadIdx.x & 63, vh8, vx, dinv, rowptr, ew, outh_bf, outh_f8, outx);
}

__global__ void __launch_bounds__(256) k_prop64(
    const unsigned char* __restrict__ v8, const float* __restrict__ dinv,
    const int* __restrict__ rowptr, const unsigned* __restrict__ ew,
    __bf16* __restrict__ out_bf, unsigned char* __restrict__ out_f8) {
    int n = blockIdx.x * 4 + (threadIdx.x >> 6);
    if (n >= NN) return;
    prop64_body(n, threadIdx.x & 63, v8, dinv, rowptr, ew, out_bf, out_f8);
}

__global__ void __launch_bounds__(256) k_mfma_zr(
    const __bf16* __restrict__ xb, const __bf16* __restrict__ t1, const __bf16* __restrict__ t2,
    const __bf16* __restrict__ hb, const __bf16* __restrict__ h1, const __bf16* __restrict__ h2,
    const bf16x8* __restrict__ Bfrag, const float* __restrict__ biasC,
    __bf16* __restrict__ z_bf, __bf16* __restrict__ hr_bf, unsigned char* __restrict__ hr_f8) {
    int wv = (blockIdx.x * 256 + threadIdx.x) >> 6;
    if (wv >= NN / 16) return;
    zr_wave(wv, threadIdx.x & 63, xb, t1, t2, hb, h1, h2, Bfrag, biasC, z_bf, hr_bf, hr_f8);
}

__global__ void __launch_bounds__(256) k_mfma_ht(
    const __bf16* __restrict__ xb, const __bf16* __restrict__ t1, const __bf16* __restrict__ t2,
    const __bf16* __restrict__ hrb, const __bf16* __restrict__ r1, const __bf16* __restrict__ r2,
    const bf16x8* __restrict__ Bfrag, const float* __restrict__ biasC,
    const __bf16* __restrict__ z_bf, const float* __restrict__ h0,
    const float* __restrict__ Wlin, const float* __restrict__ blin,
    float* __restrict__ hout, float* __restrict__ yout) {
    int wv = (blockIdx.x * 256 + threadIdx.x) >> 6;
    if (wv >= NN / 16) return;
    ht_wave(wv, threadIdx.x & 63, xb, t1, t2, hrb, r1, r2, Bfrag, biasC, z_bf, h0,
            Wlin, blin, hout, yout);
}

// ============================= launch =============================

extern "C" void kernel_launch(void* const* d_in, const int* in_sizes, int n_in,
                              void* d_out, int out_size, void* d_ws, size_t ws_size,
                              hipStream_t stream) {
    (void)in_sizes; (void)n_in; (void)out_size; (void)ws_size;
    const float* x    = (const float*)d_in[0];
    const int*   eidx = (const int*)d_in[1];
    const float* ew   = (const float*)d_in[2];
    const float* h0   = (const float*)d_in[3];
    const float* Wx   = (const float*)d_in[4];
    const float* Wh   = (const float*)d_in[5];
    const float* bx   = (const float*)d_in[6];
    const float* bh   = (const float*)d_in[7];
    const float* Wlin = (const float*)d_in[8];
    const float* blin = (const float*)d_in[9];
    const int* src = eidx;
    const int* dst = eidx + NE;

    char* ws = (char*)d_ws;
    size_t off = 0;
    auto alloc = [&](size_t nbytes) -> void* {
        void* p = ws + off;
        off += (nbytes + 255) & ~(size_t)255;
        return p;
    };
    int*    Cd      = (int*)alloc((size_t)TBL * 4);
    int*    Cs      = (int*)alloc((size_t)TBL * 4);
    int*    CdRow   = (int*)alloc(NBUCK * 4);
    int*    CsRow   = (int*)alloc(NBUCK * 4);
    int*    CdBase  = (int*)alloc(NBUCK * 4);
    int*    CsBase  = (int*)alloc(NBUCK * 4);
    uint2*  drec    = (uint2*)alloc((size_t)NE * 8);
    unsigned* srec  = (unsigned*)alloc((size_t)NE * 4);
    float*  dinv    = (float*)alloc(NN * 4);
    int*    rowptr  = (int*)alloc((NN + 1) * 4);
    unsigned* csr_ew = (unsigned*)alloc((size_t)NE * 4);
    __bf16* x_bf    = (__bf16*)alloc((size_t)NN * CI * 2);
    __bf16* h0_bf   = (__bf16*)alloc((size_t)NN * CO * 2);
    unsigned char* h0_f8 = (unsigned char*)alloc((size_t)NN * CO);
    unsigned char* T1_f8 = (unsigned char*)alloc((size_t)NN * CO);
    unsigned char* hr_f8 = (unsigned char*)alloc((size_t)NN * CO);
    __bf16* Tx1     = (__bf16*)alloc((size_t)NN * CI * 2);
    __bf16* Tx2     = (__bf16*)alloc((size_t)NN * CI * 2);
    __bf16* Th1     = (__bf16*)alloc((size_t)NN * CO * 2);
    __bf16* Th2     = (__bf16*)alloc((size_t)NN * CO * 2);
    __bf16* hr_bf   = (__bf16*)alloc((size_t)NN * CO * 2);
    __bf16* z_bf    = (__bf16*)alloc((size_t)NN * CO * 2);
    bf16x8* BfragZR = (bf16x8*)alloc(4096 * 16);
    bf16x8* BfragHT = (bf16x8*)alloc(2048 * 16);
    float*  biasC   = (float*)alloc(192 * 4);

    float* hout = (float*)d_out;
    float* yout = hout + (size_t)NN * CO;

    // ---- preferred path: single cooperative megakernel ----
    MegaArgs ma;
    ma.src = src; ma.dst = dst; ma.ew = ew; ma.x = x; ma.h0 = h0;
    ma.Wx = Wx; ma.Wh = Wh; ma.bx = bx; ma.bh = bh; ma.Wlin = Wlin; ma.blin = blin;
    ma.Cd = Cd; ma.Cs = Cs; ma.CdRow = CdRow; ma.CsRow = CsRow;
    ma.CdBase = CdBase; ma.CsBase = CsBase;
    ma.drec = drec; ma.srec = srec; ma.dinv = dinv; ma.rowptr = rowptr; ma.csr_ew = csr_ew;
    ma.x_bf = x_bf; ma.h0_bf = h0_bf; ma.h0_f8 = h0_f8;
    ma.T1_f8 = T1_f8; ma.hr_f8 = hr_f8;
    ma.Tx1 = Tx1; ma.Tx2 = Tx2; ma.Th1 = Th1; ma.Th2 = Th2;
    ma.hr_bf = hr_bf; ma.z_bf = z_bf;
    ma.BfragZR = BfragZR; ma.BfragHT = BfragHT; ma.biasC = biasC;
    ma.hout = hout; ma.yout = yout;

    int mp = 0;
    hipError_t qe = hipOccupancyMaxActiveBlocksPerMultiprocessor(&mp, k_mega, 256, 0);
    int grid = (qe == hipSuccess && mp > 0) ? mp * 256 : 0;
    if (grid > 2048) grid = 2048;
    hipError_t le = hipErrorUnknown;
    if (grid >= 8) {
        void* kp[] = { (void*)&ma };
        le = hipLaunchCooperativeKernel(k_mega, dim3((unsigned)grid), dim3(256), kp, 0u, stream);
    }
    if (le == hipSuccess) return;

    // ---- fallback: previous verified 10-kernel pipeline ----
    const int PROPB = (NN + 3) / 4;
    const int GEMMB = (NN / 16 * 64 + 255) / 256;

    k_count<<<NBLK3 + CB + 25, 256, 0, stream>>>(
        src, dst, Cd, Cs, x, h0, x_bf, h0_bf, h0_f8,
        Wx, Wh, bx, bh, BfragZR, BfragHT, biasC);
    k_scan_tables<<<2, 1024, 0, stream>>>(Cd, Cs);
    k_scatter<<<NBLK3, 256, 0, stream>>>(src, dst, ew, Cd, Cs, drec, srec);
    k_dinv<<<NBUCK, 256, 0, stream>>>(Cs, srec, dinv);
    k_build<<<NBUCK, 256, 0, stream>>>(Cd, drec, dinv, rowptr, csr_ew);

    k_fprop<<<PROPB, 256, 0, stream>>>(h0_f8, x_bf, dinv, rowptr, csr_ew, Th1, T1_f8, Tx1);
    k_fprop<<<PROPB, 256, 0, stream>>>(T1_f8, Tx1, dinv, rowptr, csr_ew, Th2, nullptr, Tx2);

    k_mfma_zr<<<GEMMB, 256, 0, stream>>>(x_bf, Tx1, Tx2, h0_bf, Th1, Th2,
                                         BfragZR, biasC, z_bf, hr_bf, hr_f8);
    k_prop64<<<PROPB, 256, 0, stream>>>(hr_f8, dinv, rowptr, csr_ew, Th1, T1_f8);
    k_prop64<<<PROPB, 256, 0, stream>>>(T1_f8, dinv, rowptr, csr_ew, Th2, nullptr);
    k_mfma_ht<<<GEMMB, 256, 0, stream>>>(x_bf, Tx1, Tx2, hr_bf, Th1, Th2,
                                         BfragHT, biasC, z_bf, h0, Wlin, blin, hout, yout);
}

// Round 7
// 307.004 us; speedup vs baseline: 2.9046x; 2.9046x over previous
//
#include <hip/hip_runtime.h>

// Problem constants (from reference)
constexpr int NN = 50000;   // nodes
constexpr int NE = 800000;  // edges
constexpr int CI = 16;      // in channels
constexpr int CO = 64;      // out channels
constexpr int DD = 7;       // decoder dim

// Binned counting-sort geometry (no global atomics anywhere)
constexpr int NBUCK = 196;                       // node buckets: n>>8, 50000/256
constexpr int EPB   = 4096;                      // edges per binning block
constexpr int NBLK3 = (NE + EPB - 1) / EPB;      // 196 binning blocks
constexpr int TBL   = NBUCK * NBLK3;             // 38416 table entries

typedef __bf16 bf16x8 __attribute__((ext_vector_type(8)));
typedef float  f32x4  __attribute__((ext_vector_type(4)));
typedef float  f32x2  __attribute__((ext_vector_type(2)));

__device__ inline float blo(unsigned u) { return __uint_as_float(u << 16); }
__device__ inline float bhi(unsigned u) { return __uint_as_float(u & 0xffff0000u); }

// fp8 e4m3 helpers (HW packed converts; OCP format on gfx950)
__device__ inline void acc8_fp8(float acc[8], float w, uint2 u) {
    f32x2 c;
    c = __builtin_amdgcn_cvt_pk_f32_fp8(u.x, false); acc[0] += w * c[0]; acc[1] += w * c[1];
    c = __builtin_amdgcn_cvt_pk_f32_fp8(u.x, true);  acc[2] += w * c[0]; acc[3] += w * c[1];
    c = __builtin_amdgcn_cvt_pk_f32_fp8(u.y, false); acc[4] += w * c[0]; acc[5] += w * c[1];
    c = __builtin_amdgcn_cvt_pk_f32_fp8(u.y, true);  acc[6] += w * c[0]; acc[7] += w * c[1];
}
__device__ inline uint2 pack_fp8x8(const float o[8]) {
    int t0 = __builtin_amdgcn_cvt_pk_fp8_f32(o[0], o[1], 0, false);
    t0 = __builtin_amdgcn_cvt_pk_fp8_f32(o[2], o[3], t0, true);
    int t1 = __builtin_amdgcn_cvt_pk_fp8_f32(o[4], o[5], 0, false);
    t1 = __builtin_amdgcn_cvt_pk_fp8_f32(o[6], o[7], t1, true);
    uint2 r; r.x = (unsigned)t0; r.y = (unsigned)t1; return r;
}
__device__ inline unsigned char fp8_of(float v) {
    return (unsigned char)(__builtin_amdgcn_cvt_pk_fp8_f32(v, v, 0, false) & 0xff);
}

// ============== pass 1: bucket histograms + casts + B-prep (fused) ==============
// B-prep folds the Chebyshev recursion into the weights (A = [T0, P, P^2];
// W'0 = W0 - W2, W'1 = W1, W'2 = 2*W2) so all props are pure gathers.

constexpr int XOCT = NN * CI / 8;              // 100000 octets in x
constexpr int HOCT = NN * CO / 8;              // 400000 octets in h0
constexpr int CB = (XOCT + HOCT + 255) / 256;  // 1954 cast blocks

__global__ void __launch_bounds__(256) k_count(
    const int* __restrict__ src, const int* __restrict__ dst,
    int* __restrict__ Cd, int* __restrict__ Cs,
    const float* __restrict__ x, const float* __restrict__ h0,
    __bf16* __restrict__ x_bf, __bf16* __restrict__ h0_bf, unsigned char* __restrict__ h0_f8,
    const float* __restrict__ Wx, const float* __restrict__ Wh,
    const float* __restrict__ bx, const float* __restrict__ bh,
    bf16x8* __restrict__ BfragZR, bf16x8* __restrict__ BfragHT, float* __restrict__ biasC) {
    int b = blockIdx.x;
    if (b < NBLK3) {
        __shared__ int hd[NBUCK], hs[NBUCK];
        for (int i = threadIdx.x; i < NBUCK; i += 256) { hd[i] = 0; hs[i] = 0; }
        __syncthreads();
        int base = b * EPB;
#pragma unroll
        for (int k = 0; k < EPB / 256; k++) {
            int e = base + k * 256 + threadIdx.x;
            if (e < NE) {
                int s = src[e], d = dst[e];
                atomicAdd(&hd[d >> 8], 1);
                atomicAdd(&hs[s >> 8], 1);
            }
        }
        __syncthreads();
        for (int i = threadIdx.x; i < NBUCK; i += 256) {
            Cd[i * NBLK3 + b] = hd[i];
            Cs[i * NBLK3 + b] = hs[i];
        }
    } else if (b < NBLK3 + CB) {
        int t = (b - NBLK3) * 256 + threadIdx.x;  // octet index
        if (t < XOCT) {
            const float* sp = x + (size_t)t * 8;
            float4 a = *(const float4*)sp;
            float4 c = *(const float4*)(sp + 4);
            bf16x8 o;
            o[0] = (__bf16)a.x; o[1] = (__bf16)a.y; o[2] = (__bf16)a.z; o[3] = (__bf16)a.w;
            o[4] = (__bf16)c.x; o[5] = (__bf16)c.y; o[6] = (__bf16)c.z; o[7] = (__bf16)c.w;
            *(bf16x8*)(x_bf + (size_t)t * 8) = o;
        } else if (t < XOCT + HOCT) {
            int u = t - XOCT;
            const float* sp = h0 + (size_t)u * 8;
            float4 a = *(const float4*)sp;
            float4 c = *(const float4*)(sp + 4);
            bf16x8 o;
            o[0] = (__bf16)a.x; o[1] = (__bf16)a.y; o[2] = (__bf16)a.z; o[3] = (__bf16)a.w;
            o[4] = (__bf16)c.x; o[5] = (__bf16)c.y; o[6] = (__bf16)c.z; o[7] = (__bf16)c.w;
            *(bf16x8*)(h0_bf + (size_t)u * 8) = o;
            float f[8] = {a.x, a.y, a.z, a.w, c.x, c.y, c.z, c.w};
            *(uint2*)(h0_f8 + (size_t)u * 8) = pack_fp8x8(f);
        }
    } else {
        int tid = (b - NBLK3 - CB) * 256 + threadIdx.x;
        if (tid < 6144) {
            int e = tid, gate, n, kk, l;
            if (e < 4096) {
                int t = e >> 9, rem = e & 511;
                kk = rem >> 6; l = rem & 63;
                n = t * 16 + (l & 15);
                gate = n >> 6;
            } else {
                int e2 = e - 4096;
                int t = e2 >> 9, rem = e2 & 511;
                kk = rem >> 6; l = rem & 63;
                n = t * 16 + (l & 15);
                gate = 2;
            }
            int co = n & 63;
            int k0 = kk * 32 + (l >> 4) * 8;
            bf16x8 f;
#pragma unroll
            for (int j = 0; j < 8; j++) {
                int k = k0 + j;
                float w = 0.f;
                if (k < 48) {
                    int kb = k >> 4, ci = k & 15;
                    const float* Wg = Wx + gate * 3 * 16 * 64;
                    float w0 = Wg[(kb * 16 + ci) * 64 + co];
                    if (kb == 0)      w = w0 - Wg[(2 * 16 + ci) * 64 + co];
                    else if (kb == 1) w = w0;
                    else              w = 2.f * w0;
                } else if (k < 240) {
                    int kh = k - 48, kb = kh >> 6, ci = kh & 63;
                    const float* Wg = Wh + gate * 3 * 64 * 64;
                    float w0 = Wg[(kb * 64 + ci) * 64 + co];
                    if (kb == 0)      w = w0 - Wg[(2 * 64 + ci) * 64 + co];
                    else if (kb == 1) w = w0;
                    else              w = 2.f * w0;
                }
                f[j] = (__bf16)w;
            }
            if (e < 4096) BfragZR[e] = f; else BfragHT[e - 4096] = f;
        } else if (tid < 6144 + 192) {
            int i = tid - 6144;
            biasC[i] = bx[i] + bh[i];
        }
    }
}

// ============== pass 2: flat exclusive scan of both tables (in place) ==============

__global__ void __launch_bounds__(1024) k_scan_tables(int* __restrict__ Cd, int* __restrict__ Cs) {
    int* C = (blockIdx.x == 0) ? Cd : Cs;
    constexpr int CHUNK = (TBL + 1023) / 1024;  // 38
    __shared__ int part[1024];
    int t = threadIdx.x;
    int base = t * CHUNK;
    int v[CHUNK];
    int s = 0;
#pragma unroll
    for (int j = 0; j < CHUNK; j++) {
        int idx = base + j;
        int xv = (idx < TBL) ? C[idx] : 0;
        v[j] = s;  // exclusive within chunk
        s += xv;
    }
    part[t] = s;
    __syncthreads();
    for (int off = 1; off < 1024; off <<= 1) {
        int p = (t >= off) ? part[t - off] : 0;
        __syncthreads();
        part[t] += p;
        __syncthreads();
    }
    int tb = (t > 0) ? part[t - 1] : 0;
#pragma unroll
    for (int j = 0; j < CHUNK; j++) {
        int idx = base + j;
        if (idx < TBL) C[idx] = tb + v[j];
    }
}

// ============== pass 3: scatter edge records into bucket segments ==============
// dst-record: {s | bf16(w)<<16, d&255}  (feeds CSR build)
// src-record (4B): top-24 bits of f32 w | (s&255)  (feeds degree/dinv; w trunc err 2^-16)

__global__ void __launch_bounds__(256) k_scatter(
    const int* __restrict__ src, const int* __restrict__ dst, const float* __restrict__ ew,
    const int* __restrict__ Cd, const int* __restrict__ Cs,
    uint2* __restrict__ drec, unsigned* __restrict__ srec) {
    __shared__ int cd[NBUCK], cs[NBUCK];
    int b = blockIdx.x;
    for (int i = threadIdx.x; i < NBUCK; i += 256) {
        cd[i] = Cd[i * NBLK3 + b];
        cs[i] = Cs[i * NBLK3 + b];
    }
    __syncthreads();
    int base = b * EPB;
#pragma unroll
    for (int k = 0; k < EPB / 256; k++) {
        int e = base + k * 256 + threadIdx.x;
        if (e < NE) {
            int s = src[e], d = dst[e];
            float w = (s == d) ? 0.f : ew[e];
            __bf16 wb = (__bf16)w;
            unsigned wu = (unsigned)__builtin_bit_cast(unsigned short, wb);
            int pd = atomicAdd(&cd[d >> 8], 1);
            drec[pd] = make_uint2((unsigned)s | (wu << 16), (unsigned)(d & 255));
            int ps = atomicAdd(&cs[s >> 8], 1);
            srec[ps] = (__builtin_bit_cast(unsigned, w) & 0xFFFFFF00u) | (unsigned)(s & 255);
        }
    }
}

// ============== pass 4b: per-src-bucket degree accumulation -> dinv ==============

__global__ void __launch_bounds__(256) k_dinv(
    const int* __restrict__ Cs, const unsigned* __restrict__ srec, float* __restrict__ dinv) {
    int bkt = blockIdx.x;
    __shared__ float acc[256];
    acc[threadIdx.x] = 0.f;
    __syncthreads();
    int beg = Cs[bkt * NBLK3];
    int end = (bkt == NBUCK - 1) ? NE : Cs[(bkt + 1) * NBLK3];
    for (int i = beg + threadIdx.x; i < end; i += 256) {
        unsigned r = srec[i];
        atomicAdd(&acc[r & 255], __uint_as_float(r & 0xFFFFFF00u));
    }
    __syncthreads();
    int node = bkt * 256 + threadIdx.x;
    if (node < NN) {
        float dsum = acc[threadIdx.x];
        dinv[node] = (dsum > 0.f) ? (1.f / sqrtf(dsum)) : 0.f;
    }
}

// ====== pass 4a: per-dst-bucket counting sort -> rowptr + csr_ew (dinv folded) ======

__global__ void __launch_bounds__(256) k_build(
    const int* __restrict__ Cd, const uint2* __restrict__ drec, const float* __restrict__ dinv,
    int* __restrict__ rowptr, unsigned* __restrict__ csr_ew) {
    int bkt = blockIdx.x;
    __shared__ int cnt[256], sc[256], cur[256];
    int t = threadIdx.x;
    cnt[t] = 0;
    __syncthreads();
    int beg = Cd[bkt * NBLK3];
    int end = (bkt == NBUCK - 1) ? NE : Cd[(bkt + 1) * NBLK3];
    for (int i = beg + t; i < end; i += 256) atomicAdd(&cnt[drec[i].y], 1);
    __syncthreads();
    int val = cnt[t];
    sc[t] = val;
    __syncthreads();
    for (int off = 1; off < 256; off <<= 1) {
        int p = (t >= off) ? sc[t - off] : 0;
        __syncthreads();
        sc[t] += p;
        __syncthreads();
    }
    int ex = sc[t] - val;  // exclusive scan
    int node = bkt * 256 + t;
    if (node <= NN) rowptr[node] = beg + ex;  // node==NN lands on rowptr[NN]=NE
    cur[t] = ex;
    __syncthreads();
    for (int i = beg + t; i < end; i += 256) {
        uint2 r = drec[i];
        int slot = beg + atomicAdd(&cur[r.y], 1);
        unsigned s = r.x & 0xffff;
        float w = bhi(r.x);
        float wp = dinv[s] * w;
        __bf16 wb = (__bf16)wp;
        csr_ew[slot] = s | ((unsigned)__builtin_bit_cast(unsigned short, wb) << 16);
    }
}

// ============================= propagation bodies (pure) =============================
// out[n] = -dinv[n] * sum_{e in row n} w'_e * v[src_e]
//
// Cache budget: ew is a zero-reuse stream -> nontemporal load; gate-facing bf16
// outputs are consumed 1-2 kernels later -> nontemporal store; fp8/x outputs feed
// the NEXT kernel's gathers -> keep cached.

__device__ inline void fprop_body(int n, int lane,
                                  const unsigned char* __restrict__ vh8,
                                  const __bf16* __restrict__ vx,
                                  const float* __restrict__ dinv,
                                  const int* __restrict__ rowptr,
                                  const unsigned* __restrict__ ew,
                                  __bf16* __restrict__ outh_bf,
                                  unsigned char* __restrict__ outh_f8,
                                  __bf16* __restrict__ outx) {
    int j = lane >> 3, cg = lane & 7;
    int beg = rowptr[n], end = rowptr[n + 1];
    float f = -dinv[n];
    unsigned pmeta = (beg + lane < end) ? __builtin_nontemporal_load(ew + beg + lane) : 0u;
    int deg = end - beg;
    int nIt = (deg >= 64) ? 8 : ((deg + 7) >> 3);
    float acc[8] = {0.f, 0.f, 0.f, 0.f, 0.f, 0.f, 0.f, 0.f};
    float ax0 = 0.f, ax1 = 0.f;
#pragma unroll
    for (int t = 0; t < 8; t++) {
        if (t < nIt) {
            unsigned p = __shfl(pmeta, j + 8 * t, 64);
            float w = bhi(p);
            int s = p & 0xffff;
            uint2 u = *(const uint2*)(vh8 + (size_t)s * 64 + cg * 8);
            unsigned xv = *(const unsigned*)((const char*)vx + ((size_t)s * 32 + cg * 4));
            acc8_fp8(acc, w, u);
            ax0 += w * blo(xv);
            ax1 += w * bhi(xv);
        }
    }
    for (int e = beg + 64 + j; e < end; e += 8) {
        unsigned p = __builtin_nontemporal_load(ew + e);
        float w = bhi(p);
        int s = p & 0xffff;
        uint2 u = *(const uint2*)(vh8 + (size_t)s * 64 + cg * 8);
        unsigned xv = *(const unsigned*)((const char*)vx + ((size_t)s * 32 + cg * 4));
        acc8_fp8(acc, w, u);
        ax0 += w * blo(xv);
        ax1 += w * bhi(xv);
    }
#pragma unroll
    for (int m = 8; m <= 32; m <<= 1) {
#pragma unroll
        for (int i = 0; i < 8; i++) acc[i] += __shfl_xor(acc[i], m, 64);
        ax0 += __shfl_xor(ax0, m, 64);
        ax1 += __shfl_xor(ax1, m, 64);
    }
    if (lane < 8) {
        float o[8];
#pragma unroll
        for (int i = 0; i < 8; i++) o[i] = f * acc[i];
        bf16x8 st;
#pragma unroll
        for (int i = 0; i < 8; i++) st[i] = (__bf16)o[i];
        __builtin_nontemporal_store(st, (bf16x8*)(outh_bf + (size_t)n * 64 + lane * 8));
        if (outh_f8) *(uint2*)(outh_f8 + (size_t)n * 64 + lane * 8) = pack_fp8x8(o);
        __bf16 b0 = (__bf16)(f * ax0), b1 = (__bf16)(f * ax1);
        unsigned pk = (unsigned)__builtin_bit_cast(unsigned short, b0)
                    | ((unsigned)__builtin_bit_cast(unsigned short, b1) << 16);
        *(unsigned*)((char*)outx + (size_t)n * 32 + lane * 4) = pk;
    }
}

__device__ inline void prop64_body(int n, int lane,
                                   const unsigned char* __restrict__ v8,
                                   const float* __restrict__ dinv,
                                   const int* __restrict__ rowptr,
                                   const unsigned* __restrict__ ew,
                                   __bf16* __restrict__ out_bf,
                                   unsigned char* __restrict__ out_f8) {
    int j = lane >> 3, cg = lane & 7;
    int beg = rowptr[n], end = rowptr[n + 1];
    float f = -dinv[n];
    unsigned pmeta = (beg + lane < end) ? __builtin_nontemporal_load(ew + beg + lane) : 0u;
    int deg = end - beg;
    int nIt = (deg >= 64) ? 8 : ((deg + 7) >> 3);
    float acc[8] = {0.f, 0.f, 0.f, 0.f, 0.f, 0.f, 0.f, 0.f};
#pragma unroll
    for (int t = 0; t < 8; t++) {
        if (t < nIt) {
            unsigned p = __shfl(pmeta, j + 8 * t, 64);
            float w = bhi(p);
            int s = p & 0xffff;
            uint2 u = *(const uint2*)(v8 + (size_t)s * 64 + cg * 8);
            acc8_fp8(acc, w, u);
        }
    }
    for (int e = beg + 64 + j; e < end; e += 8) {
        unsigned p = __builtin_nontemporal_load(ew + e);
        float w = bhi(p);
        int s = p & 0xffff;
        uint2 u = *(const uint2*)(v8 + (size_t)s * 64 + cg * 8);
        acc8_fp8(acc, w, u);
    }
#pragma unroll
    for (int m = 8; m <= 32; m <<= 1) {
#pragma unroll
        for (int i = 0; i < 8; i++) acc[i] += __shfl_xor(acc[i], m, 64);
    }
    if (lane < 8) {
        float o[8];
#pragma unroll
        for (int i = 0; i < 8; i++) o[i] = f * acc[i];
        bf16x8 st;
#pragma unroll
        for (int i = 0; i < 8; i++) st[i] = (__bf16)o[i];
        __builtin_nontemporal_store(st, (bf16x8*)(out_bf + (size_t)n * 64 + lane * 8));
        if (out_f8) *(uint2*)(out_f8 + (size_t)n * 64 + lane * 8) = pack_fp8x8(o);
    }
}

// fused stage: one wave per node does BOTH the h-prop and x-prop over one row pass
__global__ void __launch_bounds__(256) k_fprop(
    const unsigned char* __restrict__ vh8, const __bf16* __restrict__ vx,
    const float* __restrict__ dinv,
    const int* __restrict__ rowptr, const unsigned* __restrict__ ew,
    __bf16* __restrict__ outh_bf, unsigned char* __restrict__ outh_f8,
    __bf16* __restrict__ outx) {
    int n = blockIdx.x * 4 + (threadIdx.x >> 6);
    if (n >= NN) return;
    fprop_body(n, threadIdx.x & 63, vh8, vx, dinv, rowptr, ew, outh_bf, outh_f8, outx);
}

__global__ void __launch_bounds__(256) k_prop64(
    const unsigned char* __restrict__ v8, const float* __restrict__ dinv,
    const int* __restrict__ rowptr, const unsigned* __restrict__ ew,
    __bf16* __restrict__ out_bf, unsigned char* __restrict__ out_f8) {
    int n = blockIdx.x * 4 + (threadIdx.x >> 6);
    if (n >= NN) return;
    prop64_body(n, threadIdx.x & 63, v8, dinv, rowptr, ew, out_bf, out_f8);
}

// ============================= MFMA dense gates =============================
// Logical A row (K=256): [x(16)|Px(16)|P2x(16)|H(64)|PH(64)|P2H(64)|pad(16)], bf16 flat.

__device__ inline bf16x8 load_a_bf(int c, int m,
                                   const __bf16* __restrict__ xb, const __bf16* __restrict__ t1,
                                   const __bf16* __restrict__ t2, const __bf16* __restrict__ hb,
                                   const __bf16* __restrict__ h1, const __bf16* __restrict__ h2) {
    if (c >= 30) {
        bf16x8 a;
#pragma unroll
        for (int j = 0; j < 8; j++) a[j] = (__bf16)0.f;
        return a;
    }
    if (c < 6) {
        const __bf16* base = (c < 2) ? xb : ((c < 4) ? t1 : t2);
        return *(const bf16x8*)(base + (size_t)m * 16 + (c & 1) * 8);
    }
    int d = c - 6;
    const __bf16* base = (d < 8) ? hb : ((d < 16) ? h1 : h2);
    return *(const bf16x8*)(base + (size_t)m * 64 + (d & 7) * 8);
}

// z and r gates: one wave per 16-node tile, 128 output cols (8 out-tiles).
__global__ void __launch_bounds__(256) k_mfma_zr(
    const __bf16* __restrict__ xb, const __bf16* __restrict__ t1, const __bf16* __restrict__ t2,
    const __bf16* __restrict__ hb, const __bf16* __restrict__ h1, const __bf16* __restrict__ h2,
    const bf16x8* __restrict__ Bfrag, const float* __restrict__ biasC,
    __bf16* __restrict__ z_bf, __bf16* __restrict__ hr_bf, unsigned char* __restrict__ hr_f8) {
    int wv = (blockIdx.x * 256 + threadIdx.x) >> 6;
    if (wv >= NN / 16) return;
    int lane = threadIdx.x & 63;
    int q = lane >> 4, r16 = lane & 15;
    int ma = wv * 16 + r16;
    f32x4 acc[8];
#pragma unroll
    for (int t = 0; t < 8; t++) acc[t] = (f32x4){0.f, 0.f, 0.f, 0.f};
#pragma unroll
    for (int kk = 0; kk < 8; kk++) {
        bf16x8 a = load_a_bf(kk * 4 + q, ma, xb, t1, t2, hb, h1, h2);
#pragma unroll
        for (int t = 0; t < 8; t++)
            acc[t] = __builtin_amdgcn_mfma_f32_16x16x32_bf16(a, Bfrag[(t * 8 + kk) * 64 + lane], acc[t], 0, 0, 0);
    }
    int mbase = wv * 16 + q * 4;
#pragma unroll
    for (int t = 0; t < 8; t++) {
        int co = t * 16 + r16;      // 0..127
        float bias = biasC[co];
        int col = co & 63;
#pragma unroll
        for (int reg = 0; reg < 4; reg++) {
            int mm = mbase + reg;
            float p = acc[t][reg] + bias;
            float s = 1.f / (1.f + __expf(-p));
            if (t < 4) z_bf[(size_t)mm * 64 + col] = (__bf16)s;
            else {
                float hrv = s * (float)hb[(size_t)mm * 64 + col];
                hr_bf[(size_t)mm * 64 + col] = (__bf16)hrv;
                hr_f8[(size_t)mm * 64 + col] = fp8_of(hrv);
            }
        }
    }
}

// htilde gate + GRU combine + fused decoder: wave per 16-node tile.
__global__ void __launch_bounds__(256) k_mfma_ht(
    const __bf16* __restrict__ xb, const __bf16* __restrict__ t1, const __bf16* __restrict__ t2,
    const __bf16* __restrict__ hrb, const __bf16* __restrict__ r1, const __bf16* __restrict__ r2,
    const bf16x8* __restrict__ Bfrag, const float* __restrict__ biasC,
    const __bf16* __restrict__ z_bf, const float* __restrict__ h0,
    const float* __restrict__ Wlin, const float* __restrict__ blin,
    float* __restrict__ hout, float* __restrict__ yout) {
    int wv = (blockIdx.x * 256 + threadIdx.x) >> 6;
    if (wv >= NN / 16) return;
    int lane = threadIdx.x & 63;
    int q = lane >> 4, r16 = lane & 15;
    int ma = wv * 16 + r16;
    f32x4 acc[4];
#pragma unroll
    for (int t = 0; t < 4; t++) acc[t] = (f32x4){0.f, 0.f, 0.f, 0.f};
#pragma unroll
    for (int kk = 0; kk < 8; kk++) {
        bf16x8 a = load_a_bf(kk * 4 + q, ma, xb, t1, t2, hrb, r1, r2);
#pragma unroll
        for (int t = 0; t < 4; t++)
            acc[t] = __builtin_amdgcn_mfma_f32_16x16x32_bf16(a, Bfrag[(t * 8 + kk) * 64 + lane], acc[t], 0, 0, 0);
    }
    int mbase = wv * 16 + q * 4;
    float hbuf[4][4];
#pragma unroll
    for (int t = 0; t < 4; t++) {
        int co = t * 16 + r16;   // 0..63
        float bias = biasC[128 + co];
#pragma unroll
        for (int reg = 0; reg < 4; reg++) {
            int mm = mbase + reg;
            float p = acc[t][reg] + bias;
            float htl = tanhf(p);
            float zv = (float)z_bf[(size_t)mm * 64 + co];
            float h0v = h0[(size_t)mm * 64 + co];
            float hn = zv * h0v + (1.f - zv) * htl;
            hout[(size_t)mm * 64 + co] = hn;
            hbuf[t][reg] = hn;
        }
    }
    // fused y = relu(h) @ Wlin + blin
    float ya[4][DD];
#pragma unroll
    for (int reg = 0; reg < 4; reg++)
#pragma unroll
        for (int d = 0; d < DD; d++) ya[reg][d] = 0.f;
#pragma unroll
    for (int t = 0; t < 4; t++) {
        int cb = (t * 16 + r16) * DD;
        float wl[DD];
#pragma unroll
        for (int d = 0; d < DD; d++) wl[d] = Wlin[cb + d];
#pragma unroll
        for (int reg = 0; reg < 4; reg++) {
            float rh = fmaxf(hbuf[t][reg], 0.f);
#pragma unroll
            for (int d = 0; d < DD; d++) ya[reg][d] += rh * wl[d];
        }
    }
#pragma unroll
    for (int m = 1; m <= 8; m <<= 1) {
#pragma unroll
        for (int reg = 0; reg < 4; reg++)
#pragma unroll
            for (int d = 0; d < DD; d++) ya[reg][d] += __shfl_xor(ya[reg][d], m, 64);
    }
    if (r16 < DD) {
        float b = blin[r16];
#pragma unroll
        for (int reg = 0; reg < 4; reg++) {
            float v = (r16 == 0) ? ya[reg][0] : (r16 == 1) ? ya[reg][1] : (r16 == 2) ? ya[reg][2]
                    : (r16 == 3) ? ya[reg][3] : (r16 == 4) ? ya[reg][4] : (r16 == 5) ? ya[reg][5]
                    : ya[reg][6];
            yout[(size_t)(mbase + reg) * DD + r16] = v + b;
        }
    }
}

// ============================= launch =============================

extern "C" void kernel_launch(void* const* d_in, const int* in_sizes, int n_in,
                              void* d_out, int out_size, void* d_ws, size_t ws_size,
                              hipStream_t stream) {
    (void)in_sizes; (void)n_in; (void)out_size; (void)ws_size;
    const float* x    = (const float*)d_in[0];
    const int*   eidx = (const int*)d_in[1];
    const float* ew   = (const float*)d_in[2];
    const float* h0   = (const float*)d_in[3];
    const float* Wx   = (const float*)d_in[4];
    const float* Wh   = (const float*)d_in[5];
    const float* bx   = (const float*)d_in[6];
    const float* bh   = (const float*)d_in[7];
    const float* Wlin = (const float*)d_in[8];
    const float* blin = (const float*)d_in[9];
    const int* src = eidx;
    const int* dst = eidx + NE;

    char* ws = (char*)d_ws;
    size_t off = 0;
    auto alloc = [&](size_t nbytes) -> void* {
        void* p = ws + off;
        off += (nbytes + 255) & ~(size_t)255;
        return p;
    };
    int*    Cd      = (int*)alloc((size_t)TBL * 4);
    int*    Cs      = (int*)alloc((size_t)TBL * 4);
    uint2*  drec    = (uint2*)alloc((size_t)NE * 8);
    unsigned* srec  = (unsigned*)alloc((size_t)NE * 4);
    float*  dinv    = (float*)alloc(NN * 4);
    int*    rowptr  = (int*)alloc((NN + 1) * 4);
    unsigned* csr_ew = (unsigned*)alloc((size_t)NE * 4);
    __bf16* x_bf    = (__bf16*)alloc((size_t)NN * CI * 2);
    __bf16* h0_bf   = (__bf16*)alloc((size_t)NN * CO * 2);
    unsigned char* h0_f8 = (unsigned char*)alloc((size_t)NN * CO);
    unsigned char* T1_f8 = (unsigned char*)alloc((size_t)NN * CO);
    unsigned char* hr_f8 = (unsigned char*)alloc((size_t)NN * CO);
    __bf16* Tx1     = (__bf16*)alloc((size_t)NN * CI * 2);
    __bf16* Tx2     = (__bf16*)alloc((size_t)NN * CI * 2);
    __bf16* Th1     = (__bf16*)alloc((size_t)NN * CO * 2);
    __bf16* Th2     = (__bf16*)alloc((size_t)NN * CO * 2);
    __bf16* hr_bf   = (__bf16*)alloc((size_t)NN * CO * 2);
    __bf16* z_bf    = (__bf16*)alloc((size_t)NN * CO * 2);
    bf16x8* BfragZR = (bf16x8*)alloc(4096 * 16);
    bf16x8* BfragHT = (bf16x8*)alloc(2048 * 16);
    float*  biasC   = (float*)alloc(192 * 4);

    float* hout = (float*)d_out;
    float* yout = hout + (size_t)NN * CO;

    const int PROPB = (NN + 3) / 4;          // 4 waves/block, wave per node
    const int GEMMB = (NN / 16 * 64 + 255) / 256;

    // graph build: binned counting sort, zero global atomics
    k_count<<<NBLK3 + CB + 25, 256, 0, stream>>>(
        src, dst, Cd, Cs, x, h0, x_bf, h0_bf, h0_f8,
        Wx, Wh, bx, bh, BfragZR, BfragHT, biasC);
    k_scan_tables<<<2, 1024, 0, stream>>>(Cd, Cs);
    k_scatter<<<NBLK3, 256, 0, stream>>>(src, dst, ew, Cd, Cs, drec, srec);
    k_dinv<<<NBUCK, 256, 0, stream>>>(Cs, srec, dinv);
    k_build<<<NBUCK, 256, 0, stream>>>(Cd, drec, dinv, rowptr, csr_ew);

    // stage 1: P(h0) (bf16+fp8) AND P(x) in one pass per row
    k_fprop<<<PROPB, 256, 0, stream>>>(h0_f8, x_bf, dinv, rowptr, csr_ew, Th1, T1_f8, Tx1);
    // stage 2: P^2(h0) AND P^2(x)  (pure — recursion folded into B)
    k_fprop<<<PROPB, 256, 0, stream>>>(T1_f8, Tx1, dinv, rowptr, csr_ew, Th2, nullptr, Tx2);

    // z and r gates (r fused into hr = r*h0)
    k_mfma_zr<<<GEMMB, 256, 0, stream>>>(x_bf, Tx1, Tx2, h0_bf, Th1, Th2,
                                         BfragZR, biasC, z_bf, hr_bf, hr_f8);
    // propagate hr: P(hr), P^2(hr)
    k_prop64<<<PROPB, 256, 0, stream>>>(hr_f8, dinv, rowptr, csr_ew, Th1, T1_f8);
    k_prop64<<<PROPB, 256, 0, stream>>>(T1_f8, dinv, rowptr, csr_ew, Th2, nullptr);
    // htilde gate + GRU combine + fused decoder -> h, y
    k_mfma_ht<<<GEMMB, 256, 0, stream>>>(x_bf, Tx1, Tx2, hr_bf, Th1, Th2,
                                         BfragHT, biasC, z_bf, h0, Wlin, blin, hout, yout);
}

// Round 8
// 293.739 us; speedup vs baseline: 3.0357x; 1.0452x over previous
//
#include <hip/hip_runtime.h>

// Problem constants (from reference)
constexpr int NN = 50000;   // nodes
constexpr int NE = 800000;  // edges
constexpr int CI = 16;      // in channels
constexpr int CO = 64;      // out channels
constexpr int DD = 7;       // decoder dim

// Binned counting-sort geometry (no global atomics anywhere)
constexpr int NBUCK = 196;                       // node buckets: n>>8, 50000/256
constexpr int EPB   = 4096;                      // edges per binning block
constexpr int NBLK3 = (NE + EPB - 1) / EPB;      // 196 binning blocks
constexpr int TBL   = NBUCK * NBLK3;             // 38416 table entries

typedef __bf16 bf16x8 __attribute__((ext_vector_type(8)));
typedef float  f32x4  __attribute__((ext_vector_type(4)));
typedef float  f32x2  __attribute__((ext_vector_type(2)));

__device__ inline float blo(unsigned u) { return __uint_as_float(u << 16); }
__device__ inline float bhi(unsigned u) { return __uint_as_float(u & 0xffff0000u); }

// fp8 e4m3 helpers (HW packed converts; OCP format on gfx950)
__device__ inline void acc8_fp8(float acc[8], float w, uint2 u) {
    f32x2 c;
    c = __builtin_amdgcn_cvt_pk_f32_fp8(u.x, false); acc[0] += w * c[0]; acc[1] += w * c[1];
    c = __builtin_amdgcn_cvt_pk_f32_fp8(u.x, true);  acc[2] += w * c[0]; acc[3] += w * c[1];
    c = __builtin_amdgcn_cvt_pk_f32_fp8(u.y, false); acc[4] += w * c[0]; acc[5] += w * c[1];
    c = __builtin_amdgcn_cvt_pk_f32_fp8(u.y, true);  acc[6] += w * c[0]; acc[7] += w * c[1];
}
__device__ inline uint2 pack_fp8x8(const float o[8]) {
    int t0 = __builtin_amdgcn_cvt_pk_fp8_f32(o[0], o[1], 0, false);
    t0 = __builtin_amdgcn_cvt_pk_fp8_f32(o[2], o[3], t0, true);
    int t1 = __builtin_amdgcn_cvt_pk_fp8_f32(o[4], o[5], 0, false);
    t1 = __builtin_amdgcn_cvt_pk_fp8_f32(o[6], o[7], t1, true);
    uint2 r; r.x = (unsigned)t0; r.y = (unsigned)t1; return r;
}
__device__ inline unsigned char fp8_of(float v) {
    return (unsigned char)(__builtin_amdgcn_cvt_pk_fp8_f32(v, v, 0, false) & 0xff);
}

// ============== pass 1: bucket histograms + casts + B-prep (fused) ==============
// B-prep folds the Chebyshev recursion into the weights (A = [T0, P, P^2];
// W'0 = W0 - W2, W'1 = W1, W'2 = 2*W2) so all props are pure gathers.
// Prop-facing [h|x] data is packed per node into ONE 128B-aligned record
// [h_fp8(64) | x_bf16(32) | pad(32)] so each edge gather touches ONE cache line.

constexpr int XOCT = NN * CI / 8;              // 100000 octets in x
constexpr int HOCT = NN * CO / 8;              // 400000 octets in h0
constexpr int CB = (XOCT + HOCT + 255) / 256;  // 1954 cast blocks

__global__ void __launch_bounds__(256) k_count(
    const int* __restrict__ src, const int* __restrict__ dst,
    int* __restrict__ Cd, int* __restrict__ Cs,
    const float* __restrict__ x, const float* __restrict__ h0,
    __bf16* __restrict__ x_bf, __bf16* __restrict__ h0_bf, unsigned char* __restrict__ comb0,
    const float* __restrict__ Wx, const float* __restrict__ Wh,
    const float* __restrict__ bx, const float* __restrict__ bh,
    bf16x8* __restrict__ BfragZR, bf16x8* __restrict__ BfragHT, float* __restrict__ biasC) {
    int b = blockIdx.x;
    if (b < NBLK3) {
        __shared__ int hd[NBUCK], hs[NBUCK];
        for (int i = threadIdx.x; i < NBUCK; i += 256) { hd[i] = 0; hs[i] = 0; }
        __syncthreads();
        int base = b * EPB;
#pragma unroll
        for (int k = 0; k < EPB / 256; k++) {
            int e = base + k * 256 + threadIdx.x;
            if (e < NE) {
                int s = src[e], d = dst[e];
                atomicAdd(&hd[d >> 8], 1);
                atomicAdd(&hs[s >> 8], 1);
            }
        }
        __syncthreads();
        for (int i = threadIdx.x; i < NBUCK; i += 256) {
            Cd[i * NBLK3 + b] = hd[i];
            Cs[i * NBLK3 + b] = hs[i];
        }
    } else if (b < NBLK3 + CB) {
        int t = (b - NBLK3) * 256 + threadIdx.x;  // octet index
        if (t < XOCT) {
            const float* sp = x + (size_t)t * 8;
            float4 a = *(const float4*)sp;
            float4 c = *(const float4*)(sp + 4);
            bf16x8 o;
            o[0] = (__bf16)a.x; o[1] = (__bf16)a.y; o[2] = (__bf16)a.z; o[3] = (__bf16)a.w;
            o[4] = (__bf16)c.x; o[5] = (__bf16)c.y; o[6] = (__bf16)c.z; o[7] = (__bf16)c.w;
            *(bf16x8*)(x_bf + (size_t)t * 8) = o;
            int node = t >> 1, half = t & 1;   // x row = 2 octets of 8 bf16
            *(bf16x8*)(comb0 + (size_t)node * 128 + 64 + half * 16) = o;
        } else if (t < XOCT + HOCT) {
            int u = t - XOCT;
            const float* sp = h0 + (size_t)u * 8;
            float4 a = *(const float4*)sp;
            float4 c = *(const float4*)(sp + 4);
            bf16x8 o;
            o[0] = (__bf16)a.x; o[1] = (__bf16)a.y; o[2] = (__bf16)a.z; o[3] = (__bf16)a.w;
            o[4] = (__bf16)c.x; o[5] = (__bf16)c.y; o[6] = (__bf16)c.z; o[7] = (__bf16)c.w;
            *(bf16x8*)(h0_bf + (size_t)u * 8) = o;
            float f[8] = {a.x, a.y, a.z, a.w, c.x, c.y, c.z, c.w};
            int node = u >> 3, part = u & 7;   // h row = 8 octets of 8 fp8
            *(uint2*)(comb0 + (size_t)node * 128 + part * 8) = pack_fp8x8(f);
        }
    } else {
        int tid = (b - NBLK3 - CB) * 256 + threadIdx.x;
        if (tid < 6144) {
            int e = tid, gate, n, kk, l;
            if (e < 4096) {
                int t = e >> 9, rem = e & 511;
                kk = rem >> 6; l = rem & 63;
                n = t * 16 + (l & 15);
                gate = n >> 6;
            } else {
                int e2 = e - 4096;
                int t = e2 >> 9, rem = e2 & 511;
                kk = rem >> 6; l = rem & 63;
                n = t * 16 + (l & 15);
                gate = 2;
            }
            int co = n & 63;
            int k0 = kk * 32 + (l >> 4) * 8;
            bf16x8 f;
#pragma unroll
            for (int j = 0; j < 8; j++) {
                int k = k0 + j;
                float w = 0.f;
                if (k < 48) {
                    int kb = k >> 4, ci = k & 15;
                    const float* Wg = Wx + gate * 3 * 16 * 64;
                    float w0 = Wg[(kb * 16 + ci) * 64 + co];
                    if (kb == 0)      w = w0 - Wg[(2 * 16 + ci) * 64 + co];
                    else if (kb == 1) w = w0;
                    else              w = 2.f * w0;
                } else if (k < 240) {
                    int kh = k - 48, kb = kh >> 6, ci = kh & 63;
                    const float* Wg = Wh + gate * 3 * 64 * 64;
                    float w0 = Wg[(kb * 64 + ci) * 64 + co];
                    if (kb == 0)      w = w0 - Wg[(2 * 64 + ci) * 64 + co];
                    else if (kb == 1) w = w0;
                    else              w = 2.f * w0;
                }
                f[j] = (__bf16)w;
            }
            if (e < 4096) BfragZR[e] = f; else BfragHT[e - 4096] = f;
        } else if (tid < 6144 + 192) {
            int i = tid - 6144;
            biasC[i] = bx[i] + bh[i];
        }
    }
}

// ============== pass 2: flat exclusive scan of both tables (in place) ==============

__global__ void __launch_bounds__(1024) k_scan_tables(int* __restrict__ Cd, int* __restrict__ Cs) {
    int* C = (blockIdx.x == 0) ? Cd : Cs;
    constexpr int CHUNK = (TBL + 1023) / 1024;  // 38
    __shared__ int part[1024];
    int t = threadIdx.x;
    int base = t * CHUNK;
    int v[CHUNK];
    int s = 0;
#pragma unroll
    for (int j = 0; j < CHUNK; j++) {
        int idx = base + j;
        int xv = (idx < TBL) ? C[idx] : 0;
        v[j] = s;  // exclusive within chunk
        s += xv;
    }
    part[t] = s;
    __syncthreads();
    for (int off = 1; off < 1024; off <<= 1) {
        int p = (t >= off) ? part[t - off] : 0;
        __syncthreads();
        part[t] += p;
        __syncthreads();
    }
    int tb = (t > 0) ? part[t - 1] : 0;
#pragma unroll
    for (int j = 0; j < CHUNK; j++) {
        int idx = base + j;
        if (idx < TBL) C[idx] = tb + v[j];
    }
}

// ============== pass 3: scatter edge records into bucket segments ==============
// dst-record: {s | bf16(w)<<16, d&255}  (feeds CSR build)
// src-record (4B): top-24 bits of f32 w | (s&255)  (feeds degree/dinv; w trunc err 2^-16)

__global__ void __launch_bounds__(256) k_scatter(
    const int* __restrict__ src, const int* __restrict__ dst, const float* __restrict__ ew,
    const int* __restrict__ Cd, const int* __restrict__ Cs,
    uint2* __restrict__ drec, unsigned* __restrict__ srec) {
    __shared__ int cd[NBUCK], cs[NBUCK];
    int b = blockIdx.x;
    for (int i = threadIdx.x; i < NBUCK; i += 256) {
        cd[i] = Cd[i * NBLK3 + b];
        cs[i] = Cs[i * NBLK3 + b];
    }
    __syncthreads();
    int base = b * EPB;
#pragma unroll
    for (int k = 0; k < EPB / 256; k++) {
        int e = base + k * 256 + threadIdx.x;
        if (e < NE) {
            int s = src[e], d = dst[e];
            float w = (s == d) ? 0.f : ew[e];
            __bf16 wb = (__bf16)w;
            unsigned wu = (unsigned)__builtin_bit_cast(unsigned short, wb);
            int pd = atomicAdd(&cd[d >> 8], 1);
            drec[pd] = make_uint2((unsigned)s | (wu << 16), (unsigned)(d & 255));
            int ps = atomicAdd(&cs[s >> 8], 1);
            srec[ps] = (__builtin_bit_cast(unsigned, w) & 0xFFFFFF00u) | (unsigned)(s & 255);
        }
    }
}

// ============== pass 4b: per-src-bucket degree accumulation -> dinv ==============

__global__ void __launch_bounds__(256) k_dinv(
    const int* __restrict__ Cs, const unsigned* __restrict__ srec, float* __restrict__ dinv) {
    int bkt = blockIdx.x;
    __shared__ float acc[256];
    acc[threadIdx.x] = 0.f;
    __syncthreads();
    int beg = Cs[bkt * NBLK3];
    int end = (bkt == NBUCK - 1) ? NE : Cs[(bkt + 1) * NBLK3];
    for (int i = beg + threadIdx.x; i < end; i += 256) {
        unsigned r = srec[i];
        atomicAdd(&acc[r & 255], __uint_as_float(r & 0xFFFFFF00u));
    }
    __syncthreads();
    int node = bkt * 256 + threadIdx.x;
    if (node < NN) {
        float dsum = acc[threadIdx.x];
        dinv[node] = (dsum > 0.f) ? (1.f / sqrtf(dsum)) : 0.f;
    }
}

// ====== pass 4a: per-dst-bucket counting sort -> rowptr + csr_ew (dinv folded) ======

__global__ void __launch_bounds__(256) k_build(
    const int* __restrict__ Cd, const uint2* __restrict__ drec, const float* __restrict__ dinv,
    int* __restrict__ rowptr, unsigned* __restrict__ csr_ew) {
    int bkt = blockIdx.x;
    __shared__ int cnt[256], sc[256], cur[256];
    int t = threadIdx.x;
    cnt[t] = 0;
    __syncthreads();
    int beg = Cd[bkt * NBLK3];
    int end = (bkt == NBUCK - 1) ? NE : Cd[(bkt + 1) * NBLK3];
    for (int i = beg + t; i < end; i += 256) atomicAdd(&cnt[drec[i].y], 1);
    __syncthreads();
    int val = cnt[t];
    sc[t] = val;
    __syncthreads();
    for (int off = 1; off < 256; off <<= 1) {
        int p = (t >= off) ? sc[t - off] : 0;
        __syncthreads();
        sc[t] += p;
        __syncthreads();
    }
    int ex = sc[t] - val;  // exclusive scan
    int node = bkt * 256 + t;
    if (node <= NN) rowptr[node] = beg + ex;  // node==NN lands on rowptr[NN]=NE
    cur[t] = ex;
    __syncthreads();
    for (int i = beg + t; i < end; i += 256) {
        uint2 r = drec[i];
        int slot = beg + atomicAdd(&cur[r.y], 1);
        unsigned s = r.x & 0xffff;
        float w = bhi(r.x);
        float wp = dinv[s] * w;
        __bf16 wb = (__bf16)wp;
        csr_ew[slot] = s | ((unsigned)__builtin_bit_cast(unsigned short, wb) << 16);
    }
}

// ============================= propagation bodies (pure) =============================
// out[n] = -dinv[n] * sum_{e in row n} w'_e * v[src_e]
//
// Row metadata preloaded with one coalesced load; gather loop gets meta via __shfl
// so all v-gathers pipeline. Padded lanes carry w=+0,s=0 (no-op).
// fprop gathers from ONE 128B packed record [h_fp8|x_bf16|pad] per edge.

__device__ inline void fprop_body(int n, int lane,
                                  const unsigned char* __restrict__ comb,   // [NN][128]
                                  const float* __restrict__ dinv,
                                  const int* __restrict__ rowptr,
                                  const unsigned* __restrict__ ew,
                                  __bf16* __restrict__ outh_bf,
                                  unsigned char* __restrict__ comb_out,     // nullable
                                  __bf16* __restrict__ outx) {
    int j = lane >> 3, cg = lane & 7;
    int beg = rowptr[n], end = rowptr[n + 1];
    float f = -dinv[n];
    unsigned pmeta = (beg + lane < end) ? ew[beg + lane] : 0u;
    int deg = end - beg;
    int nIt = (deg >= 64) ? 8 : ((deg + 7) >> 3);
    float acc[8] = {0.f, 0.f, 0.f, 0.f, 0.f, 0.f, 0.f, 0.f};
    float ax0 = 0.f, ax1 = 0.f;
#pragma unroll
    for (int t = 0; t < 8; t++) {
        if (t < nIt) {
            unsigned p = __shfl(pmeta, j + 8 * t, 64);
            float w = bhi(p);
            int s = p & 0xffff;
            const unsigned char* rec = comb + (size_t)s * 128;
            uint2 u = *(const uint2*)(rec + cg * 8);
            unsigned xv = *(const unsigned*)(rec + 64 + cg * 4);
            acc8_fp8(acc, w, u);
            ax0 += w * blo(xv);
            ax1 += w * bhi(xv);
        }
    }
    // rare fallback for deg > 64
    for (int e = beg + 64 + j; e < end; e += 8) {
        unsigned p = ew[e];
        float w = bhi(p);
        int s = p & 0xffff;
        const unsigned char* rec = comb + (size_t)s * 128;
        uint2 u = *(const uint2*)(rec + cg * 8);
        unsigned xv = *(const unsigned*)(rec + 64 + cg * 4);
        acc8_fp8(acc, w, u);
        ax0 += w * blo(xv);
        ax1 += w * bhi(xv);
    }
#pragma unroll
    for (int m = 8; m <= 32; m <<= 1) {
#pragma unroll
        for (int i = 0; i < 8; i++) acc[i] += __shfl_xor(acc[i], m, 64);
        ax0 += __shfl_xor(ax0, m, 64);
        ax1 += __shfl_xor(ax1, m, 64);
    }
    if (lane < 8) {
        float o[8];
#pragma unroll
        for (int i = 0; i < 8; i++) o[i] = f * acc[i];
        bf16x8 st;
#pragma unroll
        for (int i = 0; i < 8; i++) st[i] = (__bf16)o[i];
        *(bf16x8*)(outh_bf + (size_t)n * 64 + lane * 8) = st;
        __bf16 b0 = (__bf16)(f * ax0), b1 = (__bf16)(f * ax1);
        unsigned pk = (unsigned)__builtin_bit_cast(unsigned short, b0)
                    | ((unsigned)__builtin_bit_cast(unsigned short, b1) << 16);
        *(unsigned*)((char*)outx + (size_t)n * 32 + lane * 4) = pk;
        if (comb_out) {
            unsigned char* orec = comb_out + (size_t)n * 128;
            *(uint2*)(orec + lane * 8) = pack_fp8x8(o);
            *(unsigned*)(orec + 64 + lane * 4) = pk;
        }
    }
}

__device__ inline void prop64_body(int n, int lane,
                                   const unsigned char* __restrict__ v8,
                                   const float* __restrict__ dinv,
                                   const int* __restrict__ rowptr,
                                   const unsigned* __restrict__ ew,
                                   __bf16* __restrict__ out_bf,
                                   unsigned char* __restrict__ out_f8) {
    int j = lane >> 3, cg = lane & 7;
    int beg = rowptr[n], end = rowptr[n + 1];
    float f = -dinv[n];
    unsigned pmeta = (beg + lane < end) ? ew[beg + lane] : 0u;
    int deg = end - beg;
    int nIt = (deg >= 64) ? 8 : ((deg + 7) >> 3);
    float acc[8] = {0.f, 0.f, 0.f, 0.f, 0.f, 0.f, 0.f, 0.f};
#pragma unroll
    for (int t = 0; t < 8; t++) {
        if (t < nIt) {
            unsigned p = __shfl(pmeta, j + 8 * t, 64);
            float w = bhi(p);
            int s = p & 0xffff;
            uint2 u = *(const uint2*)(v8 + (size_t)s * 64 + cg * 8);
            acc8_fp8(acc, w, u);
        }
    }
    for (int e = beg + 64 + j; e < end; e += 8) {
        unsigned p = ew[e];
        float w = bhi(p);
        int s = p & 0xffff;
        uint2 u = *(const uint2*)(v8 + (size_t)s * 64 + cg * 8);
        acc8_fp8(acc, w, u);
    }
#pragma unroll
    for (int m = 8; m <= 32; m <<= 1) {
#pragma unroll
        for (int i = 0; i < 8; i++) acc[i] += __shfl_xor(acc[i], m, 64);
    }
    if (lane < 8) {
        float o[8];
#pragma unroll
        for (int i = 0; i < 8; i++) o[i] = f * acc[i];
        bf16x8 st;
#pragma unroll
        for (int i = 0; i < 8; i++) st[i] = (__bf16)o[i];
        *(bf16x8*)(out_bf + (size_t)n * 64 + lane * 8) = st;
        if (out_f8) *(uint2*)(out_f8 + (size_t)n * 64 + lane * 8) = pack_fp8x8(o);
    }
}

// fused stage: one wave per node does BOTH the h-prop and x-prop over one row pass
__global__ void __launch_bounds__(256) k_fprop(
    const unsigned char* __restrict__ comb, const float* __restrict__ dinv,
    const int* __restrict__ rowptr, const unsigned* __restrict__ ew,
    __bf16* __restrict__ outh_bf, unsigned char* __restrict__ comb_out,
    __bf16* __restrict__ outx) {
    int n = blockIdx.x * 4 + (threadIdx.x >> 6);
    if (n >= NN) return;
    fprop_body(n, threadIdx.x & 63, comb, dinv, rowptr, ew, outh_bf, comb_out, outx);
}

__global__ void __launch_bounds__(256) k_prop64(
    const unsigned char* __restrict__ v8, const float* __restrict__ dinv,
    const int* __restrict__ rowptr, const unsigned* __restrict__ ew,
    __bf16* __restrict__ out_bf, unsigned char* __restrict__ out_f8) {
    int n = blockIdx.x * 4 + (threadIdx.x >> 6);
    if (n >= NN) return;
    prop64_body(n, threadIdx.x & 63, v8, dinv, rowptr, ew, out_bf, out_f8);
}

// ============================= MFMA dense gates =============================
// Logical A row (K=256): [x(16)|Px(16)|P2x(16)|H(64)|PH(64)|P2H(64)|pad(16)], bf16 flat.

__device__ inline bf16x8 load_a_bf(int c, int m,
                                   const __bf16* __restrict__ xb, const __bf16* __restrict__ t1,
                                   const __bf16* __restrict__ t2, const __bf16* __restrict__ hb,
                                   const __bf16* __restrict__ h1, const __bf16* __restrict__ h2) {
    if (c >= 30) {
        bf16x8 a;
#pragma unroll
        for (int j = 0; j < 8; j++) a[j] = (__bf16)0.f;
        return a;
    }
    if (c < 6) {
        const __bf16* base = (c < 2) ? xb : ((c < 4) ? t1 : t2);
        return *(const bf16x8*)(base + (size_t)m * 16 + (c & 1) * 8);
    }
    int d = c - 6;
    const __bf16* base = (d < 8) ? hb : ((d < 16) ? h1 : h2);
    return *(const bf16x8*)(base + (size_t)m * 64 + (d & 7) * 8);
}

// z and r gates: one wave per 16-node tile, 128 output cols (8 out-tiles).
__global__ void __launch_bounds__(256) k_mfma_zr(
    const __bf16* __restrict__ xb, const __bf16* __restrict__ t1, const __bf16* __restrict__ t2,
    const __bf16* __restrict__ hb, const __bf16* __restrict__ h1, const __bf16* __restrict__ h2,
    const bf16x8* __restrict__ Bfrag, const float* __restrict__ biasC,
    __bf16* __restrict__ z_bf, __bf16* __restrict__ hr_bf, unsigned char* __restrict__ hr_f8) {
    int wv = (blockIdx.x * 256 + threadIdx.x) >> 6;
    if (wv >= NN / 16) return;
    int lane = threadIdx.x & 63;
    int q = lane >> 4, r16 = lane & 15;
    int ma = wv * 16 + r16;
    f32x4 acc[8];
#pragma unroll
    for (int t = 0; t < 8; t++) acc[t] = (f32x4){0.f, 0.f, 0.f, 0.f};
#pragma unroll
    for (int kk = 0; kk < 8; kk++) {
        bf16x8 a = load_a_bf(kk * 4 + q, ma, xb, t1, t2, hb, h1, h2);
#pragma unroll
        for (int t = 0; t < 8; t++)
            acc[t] = __builtin_amdgcn_mfma_f32_16x16x32_bf16(a, Bfrag[(t * 8 + kk) * 64 + lane], acc[t], 0, 0, 0);
    }
    int mbase = wv * 16 + q * 4;
#pragma unroll
    for (int t = 0; t < 8; t++) {
        int co = t * 16 + r16;      // 0..127
        float bias = biasC[co];
        int col = co & 63;
#pragma unroll
        for (int reg = 0; reg < 4; reg++) {
            int mm = mbase + reg;
            float p = acc[t][reg] + bias;
            float s = 1.f / (1.f + __expf(-p));
            if (t < 4) z_bf[(size_t)mm * 64 + col] = (__bf16)s;
            else {
                float hrv = s * (float)hb[(size_t)mm * 64 + col];
                hr_bf[(size_t)mm * 64 + col] = (__bf16)hrv;
                hr_f8[(size_t)mm * 64 + col] = fp8_of(hrv);
            }
        }
    }
}

// htilde gate + GRU combine + fused decoder: wave per 16-node tile.
__global__ void __launch_bounds__(256) k_mfma_ht(
    const __bf16* __restrict__ xb, const __bf16* __restrict__ t1, const __bf16* __restrict__ t2,
    const __bf16* __restrict__ hrb, const __bf16* __restrict__ r1, const __bf16* __restrict__ r2,
    const bf16x8* __restrict__ Bfrag, const float* __restrict__ biasC,
    const __bf16* __restrict__ z_bf, const float* __restrict__ h0,
    const float* __restrict__ Wlin, const float* __restrict__ blin,
    float* __restrict__ hout, float* __restrict__ yout) {
    int wv = (blockIdx.x * 256 + threadIdx.x) >> 6;
    if (wv >= NN / 16) return;
    int lane = threadIdx.x & 63;
    int q = lane >> 4, r16 = lane & 15;
    int ma = wv * 16 + r16;
    f32x4 acc[4];
#pragma unroll
    for (int t = 0; t < 4; t++) acc[t] = (f32x4){0.f, 0.f, 0.f, 0.f};
#pragma unroll
    for (int kk = 0; kk < 8; kk++) {
        bf16x8 a = load_a_bf(kk * 4 + q, ma, xb, t1, t2, hrb, r1, r2);
#pragma unroll
        for (int t = 0; t < 4; t++)
            acc[t] = __builtin_amdgcn_mfma_f32_16x16x32_bf16(a, Bfrag[(t * 8 + kk) * 64 + lane], acc[t], 0, 0, 0);
    }
    int mbase = wv * 16 + q * 4;
    float hbuf[4][4];
#pragma unroll
    for (int t = 0; t < 4; t++) {
        int co = t * 16 + r16;   // 0..63
        float bias = biasC[128 + co];
#pragma unroll
        for (int reg = 0; reg < 4; reg++) {
            int mm = mbase + reg;
            float p = acc[t][reg] + bias;
            float htl = tanhf(p);
            float zv = (float)z_bf[(size_t)mm * 64 + co];
            float h0v = h0[(size_t)mm * 64 + co];
            float hn = zv * h0v + (1.f - zv) * htl;
            hout[(size_t)mm * 64 + co] = hn;
            hbuf[t][reg] = hn;
        }
    }
    // fused y = relu(h) @ Wlin + blin
    float ya[4][DD];
#pragma unroll
    for (int reg = 0; reg < 4; reg++)
#pragma unroll
        for (int d = 0; d < DD; d++) ya[reg][d] = 0.f;
#pragma unroll
    for (int t = 0; t < 4; t++) {
        int cb = (t * 16 + r16) * DD;
        float wl[DD];
#pragma unroll
        for (int d = 0; d < DD; d++) wl[d] = Wlin[cb + d];
#pragma unroll
        for (int reg = 0; reg < 4; reg++) {
            float rh = fmaxf(hbuf[t][reg], 0.f);
#pragma unroll
            for (int d = 0; d < DD; d++) ya[reg][d] += rh * wl[d];
        }
    }
#pragma unroll
    for (int m = 1; m <= 8; m <<= 1) {
#pragma unroll
        for (int reg = 0; reg < 4; reg++)
#pragma unroll
            for (int d = 0; d < DD; d++) ya[reg][d] += __shfl_xor(ya[reg][d], m, 64);
    }
    if (r16 < DD) {
        float b = blin[r16];
#pragma unroll
        for (int reg = 0; reg < 4; reg++) {
            float v = (r16 == 0) ? ya[reg][0] : (r16 == 1) ? ya[reg][1] : (r16 == 2) ? ya[reg][2]
                    : (r16 == 3) ? ya[reg][3] : (r16 == 4) ? ya[reg][4] : (r16 == 5) ? ya[reg][5]
                    : ya[reg][6];
            yout[(size_t)(mbase + reg) * DD + r16] = v + b;
        }
    }
}

// ============================= launch =============================

extern "C" void kernel_launch(void* const* d_in, const int* in_sizes, int n_in,
                              void* d_out, int out_size, void* d_ws, size_t ws_size,
                              hipStream_t stream) {
    (void)in_sizes; (void)n_in; (void)out_size; (void)ws_size;
    const float* x    = (const float*)d_in[0];
    const int*   eidx = (const int*)d_in[1];
    const float* ew   = (const float*)d_in[2];
    const float* h0   = (const float*)d_in[3];
    const float* Wx   = (const float*)d_in[4];
    const float* Wh   = (const float*)d_in[5];
    const float* bx   = (const float*)d_in[6];
    const float* bh   = (const float*)d_in[7];
    const float* Wlin = (const float*)d_in[8];
    const float* blin = (const float*)d_in[9];
    const int* src = eidx;
    const int* dst = eidx + NE;

    char* ws = (char*)d_ws;
    size_t off = 0;
    auto alloc = [&](size_t nbytes) -> void* {
        void* p = ws + off;
        off += (nbytes + 255) & ~(size_t)255;
        return p;
    };
    int*    Cd      = (int*)alloc((size_t)TBL * 4);
    int*    Cs      = (int*)alloc((size_t)TBL * 4);
    uint2*  drec    = (uint2*)alloc((size_t)NE * 8);
    unsigned* srec  = (unsigned*)alloc((size_t)NE * 4);
    float*  dinv    = (float*)alloc(NN * 4);
    int*    rowptr  = (int*)alloc((NN + 1) * 4);
    unsigned* csr_ew = (unsigned*)alloc((size_t)NE * 4);
    unsigned char* comb0 = (unsigned char*)alloc((size_t)NN * 128);
    unsigned char* comb1 = (unsigned char*)alloc((size_t)NN * 128);
    __bf16* x_bf    = (__bf16*)alloc((size_t)NN * CI * 2);
    __bf16* h0_bf   = (__bf16*)alloc((size_t)NN * CO * 2);
    unsigned char* T1_f8 = (unsigned char*)alloc((size_t)NN * CO);
    unsigned char* hr_f8 = (unsigned char*)alloc((size_t)NN * CO);
    __bf16* Tx1     = (__bf16*)alloc((size_t)NN * CI * 2);
    __bf16* Tx2     = (__bf16*)alloc((size_t)NN * CI * 2);
    __bf16* Th1     = (__bf16*)alloc((size_t)NN * CO * 2);
    __bf16* Th2     = (__bf16*)alloc((size_t)NN * CO * 2);
    __bf16* hr_bf   = (__bf16*)alloc((size_t)NN * CO * 2);
    __bf16* z_bf    = (__bf16*)alloc((size_t)NN * CO * 2);
    bf16x8* BfragZR = (bf16x8*)alloc(4096 * 16);
    bf16x8* BfragHT = (bf16x8*)alloc(2048 * 16);
    float*  biasC   = (float*)alloc(192 * 4);

    float* hout = (float*)d_out;
    float* yout = hout + (size_t)NN * CO;

    const int PROPB = (NN + 3) / 4;          // 4 waves/block, wave per node
    const int GEMMB = (NN / 16 * 64 + 255) / 256;

    // graph build: binned counting sort, zero global atomics
    k_count<<<NBLK3 + CB + 25, 256, 0, stream>>>(
        src, dst, Cd, Cs, x, h0, x_bf, h0_bf, comb0,
        Wx, Wh, bx, bh, BfragZR, BfragHT, biasC);
    k_scan_tables<<<2, 1024, 0, stream>>>(Cd, Cs);
    k_scatter<<<NBLK3, 256, 0, stream>>>(src, dst, ew, Cd, Cs, drec, srec);
    k_dinv<<<NBUCK, 256, 0, stream>>>(Cs, srec, dinv);
    k_build<<<NBUCK, 256, 0, stream>>>(Cd, drec, dinv, rowptr, csr_ew);

    // stage 1: P(h0) AND P(x) in one pass per row (one 128B line per edge)
    k_fprop<<<PROPB, 256, 0, stream>>>(comb0, dinv, rowptr, csr_ew, Th1, comb1, Tx1);
    // stage 2: P^2(h0) AND P^2(x)  (pure — recursion folded into B)
    k_fprop<<<PROPB, 256, 0, stream>>>(comb1, dinv, rowptr, csr_ew, Th2, nullptr, Tx2);

    // z and r gates (r fused into hr = r*h0)
    k_mfma_zr<<<GEMMB, 256, 0, stream>>>(x_bf, Tx1, Tx2, h0_bf, Th1, Th2,
                                         BfragZR, biasC, z_bf, hr_bf, hr_f8);
    // propagate hr: P(hr), P^2(hr)
    k_prop64<<<PROPB, 256, 0, stream>>>(hr_f8, dinv, rowptr, csr_ew, Th1, T1_f8);
    k_prop64<<<PROPB, 256, 0, stream>>>(T1_f8, dinv, rowptr, csr_ew, Th2, nullptr);
    // htilde gate + GRU combine + fused decoder -> h, y
    k_mfma_ht<<<GEMMB, 256, 0, stream>>>(x_bf, Tx1, Tx2, hr_bf, Th1, Th2,
                                         BfragHT, biasC, z_bf, h0, Wlin, blin, hout, yout);
}